// Round 1
// baseline (3057.285 us; speedup 1.0000x reference)
//
#include <hip/hip_runtime.h>

#define TPB 256

__global__ void k_init_deg(float* __restrict__ deg, int n) {
    int i = blockIdx.x * blockDim.x + threadIdx.x;
    if (i < n) deg[i] = 1.0f;   // self-loop contributes 1 to every node's degree
}

__global__ void k_deg(const int* __restrict__ dst, float* __restrict__ deg, int E) {
    int e = blockIdx.x * blockDim.x + threadIdx.x;
    if (e < E) atomicAdd(&deg[dst[e]], 1.0f);
}

__global__ void k_rsqrt(float* __restrict__ deg, int n) {
    int i = blockIdx.x * blockDim.x + threadIdx.x;
    if (i < n) deg[i] = rsqrtf(deg[i]);   // deg >= 1 always
}

// h = x @ W1  (N x 128 @ 128 x 16), and agg1 init = h * dinv^2 (self-loop term)
__global__ __launch_bounds__(256) void k_gemm1(const float* __restrict__ x,
                                               const float* __restrict__ W1,
                                               const float* __restrict__ dinv,
                                               float* __restrict__ h,
                                               float* __restrict__ agg1, int n) {
    __shared__ float sW[128 * 16];
    __shared__ float sX[16 * 128];
    int t = threadIdx.x;
    for (int q = t; q < 2048; q += 256) sW[q] = W1[q];
    int node0 = blockIdx.x * 16;
    const float* xp = x + (size_t)node0 * 128;
    int nrem = n - node0;
    int nload = (nrem >= 16 ? 16 : nrem) * 128;
    for (int q = t; q < nload; q += 256) sX[q] = xp[q];
    __syncthreads();
    int local = t >> 4;   // node within tile
    int col = t & 15;
    int node = node0 + local;
    if (node >= n) return;
    float acc = 0.f;
#pragma unroll 8
    for (int k = 0; k < 128; k++) acc += sX[local * 128 + k] * sW[k * 16 + col];
    h[(size_t)node * 16 + col] = acc;
    float di = dinv[node];
    agg1[(size_t)node * 16 + col] = acc * di * di;
}

// layer-1 edge scatter: agg1[dst] += h[src] * dinv[src]*dinv[dst]
__global__ void k_edge1(const int* __restrict__ src, const int* __restrict__ dst,
                        const float* __restrict__ dinv, const float* __restrict__ h,
                        float* __restrict__ agg1, int E) {
    int e = blockIdx.x * blockDim.x + threadIdx.x;
    if (e >= E) return;
    int s = src[e], d = dst[e];
    float w = dinv[s] * dinv[d];
    const float4* hp = (const float4*)(h + (size_t)s * 16);
    float* ap = agg1 + (size_t)d * 16;
#pragma unroll
    for (int q = 0; q < 4; q++) {
        float4 v = hp[q];
        atomicAdd(ap + q * 4 + 0, v.x * w);
        atomicAdd(ap + q * 4 + 1, v.y * w);
        atomicAdd(ap + q * 4 + 2, v.z * w);
        atomicAdd(ap + q * 4 + 3, v.w * w);
    }
}

// h2[i] = sum_j relu(agg1[i,j]+b1[j]) * W2[j];  agg2 init = h2 * dinv^2 (self-loop)
__global__ void k_finish1(const float* __restrict__ agg1, const float* __restrict__ b1,
                          const float* __restrict__ W2, const float* __restrict__ dinv,
                          float* __restrict__ h2, float* __restrict__ agg2, int n) {
    int i = blockIdx.x * blockDim.x + threadIdx.x;
    if (i >= n) return;
    const float4* ap = (const float4*)(agg1 + (size_t)i * 16);
    float acc = 0.f;
#pragma unroll
    for (int q = 0; q < 4; q++) {
        float4 v = ap[q];
        acc += fmaxf(v.x + b1[q * 4 + 0], 0.f) * W2[q * 4 + 0];
        acc += fmaxf(v.y + b1[q * 4 + 1], 0.f) * W2[q * 4 + 1];
        acc += fmaxf(v.z + b1[q * 4 + 2], 0.f) * W2[q * 4 + 2];
        acc += fmaxf(v.w + b1[q * 4 + 3], 0.f) * W2[q * 4 + 3];
    }
    h2[i] = acc;
    float di = dinv[i];
    agg2[i] = acc * di * di;
}

// layer-2 edge scatter: agg2[dst] += h2[src] * dinv[src]*dinv[dst]
__global__ void k_edge2(const int* __restrict__ src, const int* __restrict__ dst,
                        const float* __restrict__ dinv, const float* __restrict__ h2,
                        float* __restrict__ agg2, int E) {
    int e = blockIdx.x * blockDim.x + threadIdx.x;
    if (e >= E) return;
    int s = src[e], d = dst[e];
    atomicAdd(&agg2[d], h2[s] * dinv[s] * dinv[d]);
}

// global add pool: out[batch[i]] += agg2[i] + b2
__global__ void k_pool(const float* __restrict__ agg2, const int* __restrict__ batch,
                       const float* __restrict__ b2, float* __restrict__ out, int n) {
    int i = blockIdx.x * blockDim.x + threadIdx.x;
    if (i >= n) return;
    atomicAdd(&out[batch[i]], agg2[i] + b2[0]);
}

extern "C" void kernel_launch(void* const* d_in, const int* in_sizes, int n_in,
                              void* d_out, int out_size, void* d_ws, size_t ws_size,
                              hipStream_t stream) {
    int n = in_sizes[0] / 128;         // N nodes
    int E = in_sizes[1] / 2;           // edges
    const float* x     = (const float*)d_in[0];
    const int*   ei    = (const int*)d_in[1];
    const int*   src   = ei;           // row 0
    const int*   dst   = ei + E;       // row 1
    const int*   batch = (const int*)d_in[2];
    const float* W1    = (const float*)d_in[3];
    const float* b1    = (const float*)d_in[4];
    const float* W2    = (const float*)d_in[5];
    const float* b2    = (const float*)d_in[6];
    float* out = (float*)d_out;

    float* dinv = (float*)d_ws;                 // N
    float* h    = dinv + n;                     // 16N
    float* agg1 = h + (size_t)16 * n;           // 16N
    float* h2   = agg1 + (size_t)16 * n;        // N
    float* agg2 = h2 + n;                       // N

    hipMemsetAsync(d_out, 0, (size_t)out_size * sizeof(float), stream);

    int gn = (n + TPB - 1) / TPB;
    int ge = (E + TPB - 1) / TPB;

    k_init_deg<<<gn, TPB, 0, stream>>>(dinv, n);
    k_deg<<<ge, TPB, 0, stream>>>(dst, dinv, E);
    k_rsqrt<<<gn, TPB, 0, stream>>>(dinv, n);
    k_gemm1<<<(n + 15) / 16, 256, 0, stream>>>(x, W1, dinv, h, agg1, n);
    k_edge1<<<ge, TPB, 0, stream>>>(src, dst, dinv, h, agg1, E);
    k_finish1<<<gn, TPB, 0, stream>>>(agg1, b1, W2, dinv, h2, agg2, n);
    k_edge2<<<ge, TPB, 0, stream>>>(src, dst, dinv, h2, agg2, E);
    k_pool<<<gn, TPB, 0, stream>>>(agg2, batch, b2, out, n);
}

// Round 2
// 595.794 us; speedup vs baseline: 5.1314x; 5.1314x over previous
//
#include <hip/hip_runtime.h>

#define TPB 256

// ---- CSR construction ----

__global__ void k_count(const int* __restrict__ dst, int* __restrict__ cnt, int E) {
    int e = blockIdx.x * blockDim.x + threadIdx.x;
    if (e < E) atomicAdd(&cnt[dst[e]], 1);
}

// block-level inclusive scan of cnt -> offs (holds inclusive for now), block sums -> part
__global__ __launch_bounds__(256) void k_scan1(const int* __restrict__ cnt,
                                               int* __restrict__ offs,
                                               int* __restrict__ part, int n) {
    __shared__ int s[256];
    int tid = threadIdx.x;
    int i = blockIdx.x * 256 + tid;
    int v = (i < n) ? cnt[i] : 0;
    s[tid] = v;
    __syncthreads();
    for (int o = 1; o < 256; o <<= 1) {
        int t = (tid >= o) ? s[tid - o] : 0;
        __syncthreads();
        s[tid] += t;
        __syncthreads();
    }
    if (i < n) offs[i] = s[tid];
    if (tid == 255) part[blockIdx.x] = s[255];
}

// single block: part -> exclusive prefix of block sums (nb <= 1024)
__global__ __launch_bounds__(1024) void k_scan2(int* __restrict__ part, int nb) {
    __shared__ int s[1024];
    int tid = threadIdx.x;
    int v = (tid < nb) ? part[tid] : 0;
    s[tid] = v;
    __syncthreads();
    for (int o = 1; o < 1024; o <<= 1) {
        int t = (tid >= o) ? s[tid - o] : 0;
        __syncthreads();
        s[tid] += t;
        __syncthreads();
    }
    if (tid < nb) part[tid] = s[tid] - v;   // exclusive
}

// finalize: offs -> exclusive scan, cursor = offs, dinv = rsqrt(cnt+1), offs[n] = E
__global__ void k_scan3(const int* __restrict__ cnt, int* __restrict__ offs,
                        const int* __restrict__ part, int* __restrict__ cursor,
                        float* __restrict__ dinv, int n, int E) {
    int i = blockIdx.x * blockDim.x + threadIdx.x;
    if (i >= n) return;
    int excl = offs[i] - cnt[i] + part[i >> 8];
    offs[i] = excl;
    cursor[i] = excl;
    dinv[i] = rsqrtf((float)cnt[i] + 1.0f);
    if (i == n - 1) offs[n] = E;
}

__global__ void k_scatter(const int* __restrict__ src, const int* __restrict__ dst,
                          int* __restrict__ cursor, int* __restrict__ sidx, int E) {
    int e = blockIdx.x * blockDim.x + threadIdx.x;
    if (e >= E) return;
    int pos = atomicAdd(&cursor[dst[e]], 1);
    sidx[pos] = src[e];
}

// ---- hs = (x @ W1) * dinv[node]  (N x 128 @ 128 x 16) ----
__global__ __launch_bounds__(256) void k_gemm1(const float* __restrict__ x,
                                               const float* __restrict__ W1,
                                               const float* __restrict__ dinv,
                                               float* __restrict__ hs, int n) {
    __shared__ float sW[128 * 16];
    __shared__ float sX[16 * 128];
    int t = threadIdx.x;
    for (int q = t; q < 2048; q += 256) sW[q] = W1[q];
    int node0 = blockIdx.x * 16;
    const float* xp = x + (size_t)node0 * 128;
    int nrem = n - node0;
    int nload = (nrem >= 16 ? 16 : nrem) * 128;
    for (int q = t; q < nload; q += 256) sX[q] = xp[q];
    __syncthreads();
    int local = t >> 4;
    int col = t & 15;
    int node = node0 + local;
    if (node >= n) return;
    float acc = 0.f;
#pragma unroll 8
    for (int k = 0; k < 128; k++) acc += sX[local * 128 + k] * sW[k * 16 + col];
    hs[(size_t)node * 16 + col] = acc * dinv[node];
}

// ---- layer-1 aggregate + bias + relu + W2 dot, write hw = h2 * dinv ----
// 16 threads per node; agg1[i,d] = dinv_i * (hs[i,d] + sum_{s in in(i)} hs[s,d])
__global__ __launch_bounds__(256) void k_agg1(const float* __restrict__ hs,
                                              const int* __restrict__ offs,
                                              const int* __restrict__ sidx,
                                              const float* __restrict__ dinv,
                                              const float* __restrict__ b1,
                                              const float* __restrict__ W2,
                                              float* __restrict__ hw, int n) {
    int t = blockIdx.x * blockDim.x + threadIdx.x;
    int node = t >> 4;
    int dim = t & 15;
    if (node >= n) return;
    float acc = hs[(size_t)node * 16 + dim];       // self-loop term (pre-scaled)
    int e0 = offs[node], e1 = offs[node + 1];
    for (int e = e0; e < e1; e++) {
        int s = sidx[e];
        acc += hs[s * 16 + dim];
    }
    float di = dinv[node];
    float r = fmaxf(acc * di + b1[dim], 0.f) * W2[dim];
    // reduce over the 16 dims
    for (int off = 8; off; off >>= 1) r += __shfl_down(r, off, 16);
    if (dim == 0) hw[node] = r * di;               // pre-scale for layer 2
}

// ---- layer-2 aggregate + b2 + pool ----
__global__ void k_agg2(const float* __restrict__ hw, const int* __restrict__ offs,
                       const int* __restrict__ sidx, const float* __restrict__ dinv,
                       const float* __restrict__ b2, const int* __restrict__ batch,
                       float* __restrict__ out, int n) {
    int i = blockIdx.x * blockDim.x + threadIdx.x;
    if (i >= n) return;
    float acc = hw[i];                             // self-loop
    int e0 = offs[i], e1 = offs[i + 1];
    for (int e = e0; e < e1; e++) acc += hw[sidx[e]];
    float val = acc * dinv[i] + b2[0];
    atomicAdd(&out[batch[i]], val);
}

extern "C" void kernel_launch(void* const* d_in, const int* in_sizes, int n_in,
                              void* d_out, int out_size, void* d_ws, size_t ws_size,
                              hipStream_t stream) {
    int n = in_sizes[0] / 128;
    int E = in_sizes[1] / 2;
    const float* x     = (const float*)d_in[0];
    const int*   ei    = (const int*)d_in[1];
    const int*   src   = ei;
    const int*   dst   = ei + E;
    const int*   batch = (const int*)d_in[2];
    const float* W1    = (const float*)d_in[3];
    const float* b1    = (const float*)d_in[4];
    const float* W2    = (const float*)d_in[5];
    const float* b2    = (const float*)d_in[6];
    float* out = (float*)d_out;

    // workspace carve-up (all 64B-aligned regions)
    char* p = (char*)d_ws;
    auto carve = [&](size_t bytes) {
        void* r = (void*)p;
        p += (bytes + 63) & ~(size_t)63;
        return r;
    };
    int*   cnt    = (int*)carve((size_t)n * 4);
    int*   offs   = (int*)carve((size_t)(n + 1) * 4);
    int*   cursor = (int*)carve((size_t)n * 4);
    int*   part   = (int*)carve(1024 * 4);
    int*   sidx   = (int*)carve((size_t)E * 4);
    float* dinv   = (float*)carve((size_t)n * 4);
    float* hs     = (float*)carve((size_t)n * 16 * 4);
    float* hw     = (float*)carve((size_t)n * 4);

    hipMemsetAsync(d_out, 0, (size_t)out_size * sizeof(float), stream);
    hipMemsetAsync(cnt, 0, (size_t)n * sizeof(int), stream);

    int gn = (n + TPB - 1) / TPB;
    int ge = (E + TPB - 1) / TPB;
    int nb = (n + 255) / 256;   // scan blocks (must be <= 1024)

    k_count<<<ge, TPB, 0, stream>>>(dst, cnt, E);
    k_scan1<<<nb, 256, 0, stream>>>(cnt, offs, part, n);
    k_scan2<<<1, 1024, 0, stream>>>(part, nb);
    k_scan3<<<gn, TPB, 0, stream>>>(cnt, offs, part, cursor, dinv, n, E);
    k_scatter<<<ge, TPB, 0, stream>>>(src, dst, cursor, sidx, E);
    k_gemm1<<<(n + 15) / 16, 256, 0, stream>>>(x, W1, dinv, hs, n);
    k_agg1<<<((size_t)n * 16 + 255) / 256, 256, 0, stream>>>(hs, offs, sidx, dinv, b1, W2, hw, n);
    k_agg2<<<gn, TPB, 0, stream>>>(hw, offs, sidx, dinv, b2, batch, out, n);
}

// Round 3
// 513.004 us; speedup vs baseline: 5.9596x; 1.1614x over previous
//
#include <hip/hip_runtime.h>

#define NB_MAX 512      // max buckets (n <= 131072)
#define CHUNK  32768    // edges per scatter block

// ---- bucket histogram: bcnt[b] = #edges with dst>>8 == b ----
__global__ __launch_bounds__(256) void k_hist(const int* __restrict__ dst,
                                              int* __restrict__ bcnt, int E, int nb) {
    __shared__ int h[NB_MAX];
    int t = threadIdx.x;
    for (int q = t; q < NB_MAX; q += 256) h[q] = 0;
    __syncthreads();
    for (int e = blockIdx.x * 256 + t; e < E; e += gridDim.x * 256)
        atomicAdd(&h[dst[e] >> 8], 1);
    __syncthreads();
    for (int q = t; q < nb; q += 256)
        if (h[q]) atomicAdd(&bcnt[q], h[q]);
}

// ---- single-block exclusive scan of bucket counts ----
__global__ __launch_bounds__(NB_MAX) void k_bscan(const int* __restrict__ bcnt,
                                                  int* __restrict__ boffs,
                                                  int* __restrict__ bcur, int nb) {
    __shared__ int s[NB_MAX];
    int t = threadIdx.x;
    int v = (t < nb) ? bcnt[t] : 0;
    s[t] = v;
    __syncthreads();
    for (int o = 1; o < NB_MAX; o <<= 1) {
        int u = (t >= o) ? s[t - o] : 0;
        __syncthreads();
        s[t] += u;
        __syncthreads();
    }
    if (t < nb) {
        boffs[t + 1] = s[t];
        bcur[t] = s[t] - v;     // exclusive = running cursor base
        if (t == 0) boffs[0] = 0;
    }
}

// ---- scatter edges into bucket-contiguous packed array ----
// packed = src | (dst&255)<<24 ; per-block two-phase (LDS hist -> one global
// reservation atomic per (block,bucket) -> LDS-cursor scatter)
__global__ __launch_bounds__(512) void k_scatter(const int* __restrict__ src,
                                                 const int* __restrict__ dst,
                                                 int* __restrict__ bcur,
                                                 int* __restrict__ packed,
                                                 int E, int nb) {
    __shared__ int lh[NB_MAX];
    __shared__ int lbase[NB_MAX];
    int t = threadIdx.x;
    int e0 = blockIdx.x * CHUNK;
    int e1 = min(e0 + CHUNK, E);
    for (int q = t; q < NB_MAX; q += 512) lh[q] = 0;
    __syncthreads();
    for (int e = e0 + t; e < e1; e += 512) atomicAdd(&lh[dst[e] >> 8], 1);
    __syncthreads();
    for (int q = t; q < nb; q += 512) {
        int c = lh[q];
        lbase[q] = c ? atomicAdd(&bcur[q], c) : 0;
        lh[q] = 0;              // reuse as local cursor
    }
    __syncthreads();
    for (int e = e0 + t; e < e1; e += 512) {
        int d = dst[e];
        int b = d >> 8;
        int r = atomicAdd(&lh[b], 1);
        packed[lbase[b] + r] = src[e] | ((d & 255) << 24);
    }
}

// ---- per-bucket degree count -> dinv = rsqrt(indeg+1) ----
__global__ __launch_bounds__(256) void k_dinv(const int* __restrict__ packed,
                                              const int* __restrict__ boffs,
                                              float* __restrict__ dinv, int n) {
    __shared__ int c[256];
    int t = threadIdx.x;
    int b = blockIdx.x;
    c[t] = 0;
    __syncthreads();
    int e0 = boffs[b], e1 = boffs[b + 1];
    for (int e = e0 + t; e < e1; e += 256)
        atomicAdd(&c[(unsigned)packed[e] >> 24], 1);
    __syncthreads();
    int node = (b << 8) + t;
    if (node < n) dinv[node] = rsqrtf((float)c[t] + 1.0f);
}

// ---- hs = (x @ W1) * dinv  (N x 128 @ 128 x 16) ----
__global__ __launch_bounds__(256) void k_gemm1(const float* __restrict__ x,
                                               const float* __restrict__ W1,
                                               const float* __restrict__ dinv,
                                               float* __restrict__ hs, int n) {
    __shared__ float sW[128 * 16];
    __shared__ float sX[16 * 128];
    int t = threadIdx.x;
    for (int q = t; q < 2048; q += 256) sW[q] = W1[q];
    int node0 = blockIdx.x * 16;
    const float* xp = x + (size_t)node0 * 128;
    int nrem = n - node0;
    int nload = (nrem >= 16 ? 16 : nrem) * 128;
    for (int q = t; q < nload; q += 256) sX[q] = xp[q];
    __syncthreads();
    int local = t >> 4;
    int col = t & 15;
    int node = node0 + local;
    if (node >= n) return;
    float acc = 0.f;
#pragma unroll 8
    for (int k = 0; k < 128; k++) acc += sX[local * 128 + k] * sW[k * 16 + col];
    hs[(size_t)node * 16 + col] = acc * dinv[node];
}

// ---- layer-1: per-bucket LDS aggregation + bias/relu/W2 dot -> hw = h2*dinv ----
__global__ __launch_bounds__(512) void k_agg1(const int* __restrict__ packed,
                                              const int* __restrict__ boffs,
                                              const float* __restrict__ hs,
                                              const float* __restrict__ dinv,
                                              const float* __restrict__ b1,
                                              const float* __restrict__ W2,
                                              float* __restrict__ hw, int n) {
    __shared__ float acc[256 * 17];      // stride 17: bank spread
    int t = threadIdx.x;
    for (int q = t; q < 256 * 17; q += 512) acc[q] = 0.f;
    __syncthreads();
    int b = blockIdx.x;
    int e0 = boffs[b], e1 = boffs[b + 1];
    int dim = t & 15, grp = t >> 4;      // 32 groups of 16 lanes
    for (int e = e0 + grp; e < e1; e += 32) {
        int p = packed[e];
        int s = p & 0xFFFFFF;
        int dl = (int)((unsigned)p >> 24);
        float v = hs[(size_t)s * 16 + dim];      // 64B coalesced row gather
        atomicAdd(&acc[dl * 17 + dim], v);
    }
    __syncthreads();
    if (t < 256) {
        int node = (b << 8) + t;
        if (node < n) {
            float di = dinv[node];
            float r = 0.f;
#pragma unroll
            for (int d = 0; d < 16; d++) {
                float a = acc[t * 17 + d] + hs[(size_t)node * 16 + d];  // + self
                float m = di * a + b1[d];
                r += fmaxf(m, 0.f) * W2[d];
            }
            hw[node] = r * di;           // pre-scaled for layer 2
        }
    }
}

// ---- layer-2 aggregate + b2 + segmented pool (batch is sorted) ----
__global__ __launch_bounds__(512) void k_agg2(const int* __restrict__ packed,
                                              const int* __restrict__ boffs,
                                              const float* __restrict__ hw,
                                              const float* __restrict__ dinv,
                                              const float* __restrict__ b2,
                                              const int* __restrict__ batch,
                                              float* __restrict__ out, int n) {
    __shared__ float a2[256];
    __shared__ float v[256];
    __shared__ int g[256];
    int t = threadIdx.x;
    if (t < 256) a2[t] = 0.f;
    __syncthreads();
    int b = blockIdx.x;
    int e0 = boffs[b], e1 = boffs[b + 1];
    for (int e = e0 + t; e < e1; e += 512) {
        int p = packed[e];
        atomicAdd(&a2[(unsigned)p >> 24], hw[p & 0xFFFFFF]);
    }
    __syncthreads();
    if (t < 256) {
        int node = (b << 8) + t;
        if (node < n) {
            v[t] = dinv[node] * (a2[t] + hw[node]) + b2[0];
            g[t] = batch[node];
        } else {
            v[t] = 0.f;
            g[t] = -1;
        }
    }
    __syncthreads();
    if (t < 256) {
        int gid = g[t];
        if (gid >= 0 && (t == 0 || g[t - 1] != gid)) {    // segment head
            float s = v[t];
            for (int q = t + 1; q < 256 && g[q] == gid; q++) s += v[q];
            atomicAdd(&out[gid], s);
        }
    }
}

extern "C" void kernel_launch(void* const* d_in, const int* in_sizes, int n_in,
                              void* d_out, int out_size, void* d_ws, size_t ws_size,
                              hipStream_t stream) {
    int n = in_sizes[0] / 128;
    int E = in_sizes[1] / 2;
    const float* x     = (const float*)d_in[0];
    const int*   ei    = (const int*)d_in[1];
    const int*   src   = ei;
    const int*   dst   = ei + E;
    const int*   batch = (const int*)d_in[2];
    const float* W1    = (const float*)d_in[3];
    const float* b1    = (const float*)d_in[4];
    const float* W2    = (const float*)d_in[5];
    const float* b2    = (const float*)d_in[6];
    float* out = (float*)d_out;

    char* p = (char*)d_ws;
    auto carve = [&](size_t bytes) {
        void* r = (void*)p;
        p += (bytes + 63) & ~(size_t)63;
        return r;
    };
    int*   bcnt   = (int*)carve(NB_MAX * 4);
    int*   boffs  = (int*)carve((NB_MAX + 1) * 4);
    int*   bcur   = (int*)carve(NB_MAX * 4);
    int*   packed = (int*)carve((size_t)E * 4);
    float* dinv   = (float*)carve((size_t)n * 4);
    float* hs     = (float*)carve((size_t)n * 16 * 4);
    float* hw     = (float*)carve((size_t)n * 4);

    int nb = (n + 255) >> 8;            // buckets of 256 nodes

    hipMemsetAsync(d_out, 0, (size_t)out_size * sizeof(float), stream);
    hipMemsetAsync(bcnt, 0, NB_MAX * sizeof(int), stream);

    k_hist<<<256, 256, 0, stream>>>(dst, bcnt, E, nb);
    k_bscan<<<1, NB_MAX, 0, stream>>>(bcnt, boffs, bcur, nb);
    k_scatter<<<(E + CHUNK - 1) / CHUNK, 512, 0, stream>>>(src, dst, bcur, packed, E, nb);
    k_dinv<<<nb, 256, 0, stream>>>(packed, boffs, dinv, n);
    k_gemm1<<<(n + 15) / 16, 256, 0, stream>>>(x, W1, dinv, hs, n);
    k_agg1<<<nb, 512, 0, stream>>>(packed, boffs, hs, dinv, b1, W2, hw, n);
    k_agg2<<<nb, 512, 0, stream>>>(packed, boffs, hw, dinv, b2, batch, out, n);
}

// Round 4
// 235.883 us; speedup vs baseline: 12.9610x; 2.1748x over previous
//
#include <hip/hip_runtime.h>

#define NB_MAX 512      // max buckets (n <= 131072)
#define CHUNK  32768    // edges per scatter block

// ---- bucket histogram: bcnt[b] = #edges with dst>>8 == b ----
__global__ __launch_bounds__(256) void k_hist(const int* __restrict__ dst,
                                              int* __restrict__ bcnt, int E, int nb) {
    __shared__ int h[NB_MAX];
    int t = threadIdx.x;
    for (int q = t; q < NB_MAX; q += 256) h[q] = 0;
    __syncthreads();
    for (int e = blockIdx.x * 256 + t; e < E; e += gridDim.x * 256)
        atomicAdd(&h[dst[e] >> 8], 1);
    __syncthreads();
    for (int q = t; q < nb; q += 256)
        if (h[q]) atomicAdd(&bcnt[q], h[q]);
}

// ---- single-block exclusive scan of bucket counts ----
__global__ __launch_bounds__(NB_MAX) void k_bscan(const int* __restrict__ bcnt,
                                                  int* __restrict__ boffs,
                                                  int* __restrict__ bcur, int nb) {
    __shared__ int s[NB_MAX];
    int t = threadIdx.x;
    int v = (t < nb) ? bcnt[t] : 0;
    s[t] = v;
    __syncthreads();
    for (int o = 1; o < NB_MAX; o <<= 1) {
        int u = (t >= o) ? s[t - o] : 0;
        __syncthreads();
        s[t] += u;
        __syncthreads();
    }
    if (t < nb) {
        boffs[t + 1] = s[t];
        bcur[t] = s[t] - v;
        if (t == 0) boffs[0] = 0;
    }
}

// ---- pass 1: scatter edges into bucket-contiguous packed = src | dl<<24 ----
__global__ __launch_bounds__(512) void k_scatter(const int* __restrict__ src,
                                                 const int* __restrict__ dst,
                                                 int* __restrict__ bcur,
                                                 int* __restrict__ packed,
                                                 int E, int nb) {
    __shared__ int lh[NB_MAX];
    __shared__ int lbase[NB_MAX];
    int t = threadIdx.x;
    int e0 = blockIdx.x * CHUNK;
    int e1 = min(e0 + CHUNK, E);
    for (int q = t; q < NB_MAX; q += 512) lh[q] = 0;
    __syncthreads();
    for (int e = e0 + t; e < e1; e += 512) atomicAdd(&lh[dst[e] >> 8], 1);
    __syncthreads();
    for (int q = t; q < nb; q += 512) {
        int c = lh[q];
        lbase[q] = c ? atomicAdd(&bcur[q], c) : 0;
        lh[q] = 0;
    }
    __syncthreads();
    for (int e = e0 + t; e < e1; e += 512) {
        int d = dst[e];
        int b = d >> 8;
        int r = atomicAdd(&lh[b], 1);
        packed[lbase[b] + r] = src[e] | ((d & 255) << 24);
    }
}

// ---- pass 2: within-bucket sort by dst -> sidx2 (dst-sorted src indices),
//      per-node CSR offsets noffs, and dinv = rsqrt(indeg+1) ----
__global__ __launch_bounds__(256) void k_sort2(const int* __restrict__ packed,
                                               const int* __restrict__ boffs,
                                               int* __restrict__ sidx2,
                                               int* __restrict__ noffs,
                                               float* __restrict__ dinv,
                                               int n, int E) {
    __shared__ int hist[256];
    __shared__ int scan[256];
    __shared__ int curs[256];
    int t = threadIdx.x, b = blockIdx.x;
    hist[t] = 0;
    __syncthreads();
    int e0 = boffs[b], e1 = boffs[b + 1];
    for (int e = e0 + t; e < e1; e += 256)
        atomicAdd(&hist[(unsigned)packed[e] >> 24], 1);
    __syncthreads();
    int v = hist[t];
    scan[t] = v;
    __syncthreads();
    for (int o = 1; o < 256; o <<= 1) {
        int u = (t >= o) ? scan[t - o] : 0;
        __syncthreads();
        scan[t] += u;
        __syncthreads();
    }
    int ex = scan[t] - v;               // exclusive prefix within bucket
    curs[t] = ex;
    int node = (b << 8) + t;
    if (node < n) {
        noffs[node] = e0 + ex;
        dinv[node] = rsqrtf((float)v + 1.0f);
        if (node == n - 1) noffs[n] = E;
    }
    __syncthreads();
    for (int e = e0 + t; e < e1; e += 256) {
        int p = packed[e];
        int dl = (int)((unsigned)p >> 24);
        int r = atomicAdd(&curs[dl], 1);
        sidx2[e0 + r] = p & 0xFFFFFF;
    }
}

// ---- hs = (x @ W1) * dinv  (N x 128 @ 128 x 16) ----
__global__ __launch_bounds__(256) void k_gemm1(const float* __restrict__ x,
                                               const float* __restrict__ W1,
                                               const float* __restrict__ dinv,
                                               float* __restrict__ hs, int n) {
    __shared__ float sW[128 * 16];
    __shared__ float sX[16 * 128];
    int t = threadIdx.x;
    for (int q = t; q < 2048; q += 256) sW[q] = W1[q];
    int node0 = blockIdx.x * 16;
    const float* xp = x + (size_t)node0 * 128;
    int nrem = n - node0;
    int nload = (nrem >= 16 ? 16 : nrem) * 128;
    for (int q = t; q < nload; q += 256) sX[q] = xp[q];
    __syncthreads();
    int local = t >> 4;
    int col = t & 15;
    int node = node0 + local;
    if (node >= n) return;
    float acc = 0.f;
#pragma unroll 8
    for (int k = 0; k < 128; k++) acc += sX[local * 128 + k] * sW[k * 16 + col];
    hs[(size_t)node * 16 + col] = acc * dinv[node];
}

// ---- layer-1: CSR register-accumulate (4 lanes/node, float4 each), no atomics ----
__global__ __launch_bounds__(256) void k_agg1(const float4* __restrict__ hs4,
                                              const int* __restrict__ noffs,
                                              const int* __restrict__ sidx2,
                                              const float* __restrict__ dinv,
                                              const float* __restrict__ b1,
                                              const float* __restrict__ W2,
                                              float* __restrict__ hw, int n) {
    int tid = blockIdx.x * 256 + threadIdx.x;
    int node = tid >> 2, q = tid & 3;
    if (node >= n) return;
    int e0 = noffs[node], e1 = noffs[node + 1];
    float4 acc = hs4[(size_t)node * 4 + q];       // self-loop term (pre-scaled)
    int e = e0;
    for (; e + 1 < e1; e += 2) {                  // 2 gathers in flight
        int s0 = sidx2[e], s1 = sidx2[e + 1];
        float4 a = hs4[(size_t)s0 * 4 + q];
        float4 c = hs4[(size_t)s1 * 4 + q];
        acc.x += a.x + c.x;
        acc.y += a.y + c.y;
        acc.z += a.z + c.z;
        acc.w += a.w + c.w;
    }
    if (e < e1) {
        float4 a = hs4[(size_t)sidx2[e] * 4 + q];
        acc.x += a.x; acc.y += a.y; acc.z += a.z; acc.w += a.w;
    }
    float di = dinv[node];
    const float4 bb = ((const float4*)b1)[q];
    const float4 ww = ((const float4*)W2)[q];
    float r = fmaxf(di * acc.x + bb.x, 0.f) * ww.x
            + fmaxf(di * acc.y + bb.y, 0.f) * ww.y
            + fmaxf(di * acc.z + bb.z, 0.f) * ww.z
            + fmaxf(di * acc.w + bb.w, 0.f) * ww.w;
    r += __shfl_down(r, 2, 4);
    r += __shfl_down(r, 1, 4);
    if (q == 0) hw[node] = r * di;                // pre-scaled for layer 2
}

// ---- layer-2: CSR register-accumulate + b2 + segmented pool (batch sorted) ----
__global__ __launch_bounds__(256) void k_agg2(const float* __restrict__ hw,
                                              const int* __restrict__ noffs,
                                              const int* __restrict__ sidx2,
                                              const float* __restrict__ dinv,
                                              const float* __restrict__ b2,
                                              const int* __restrict__ batch,
                                              float* __restrict__ out, int n) {
    __shared__ float v[256];
    __shared__ int g[256];
    int t = threadIdx.x;
    int i = blockIdx.x * 256 + t;
    float val = 0.f;
    int gid = -1;
    if (i < n) {
        float acc = hw[i];                        // self-loop
        int e0 = noffs[i], e1 = noffs[i + 1];
        int e = e0;
        for (; e + 1 < e1; e += 2) {
            float a = hw[sidx2[e]];
            float c = hw[sidx2[e + 1]];
            acc += a + c;
        }
        if (e < e1) acc += hw[sidx2[e]];
        val = dinv[i] * acc + b2[0];
        gid = batch[i];
    }
    v[t] = val;
    g[t] = gid;
    __syncthreads();
    if (gid >= 0 && (t == 0 || g[t - 1] != gid)) {
        float s = val;
        for (int q = t + 1; q < 256 && g[q] == gid; q++) s += v[q];
        atomicAdd(&out[gid], s);
    }
}

extern "C" void kernel_launch(void* const* d_in, const int* in_sizes, int n_in,
                              void* d_out, int out_size, void* d_ws, size_t ws_size,
                              hipStream_t stream) {
    int n = in_sizes[0] / 128;
    int E = in_sizes[1] / 2;
    const float* x     = (const float*)d_in[0];
    const int*   ei    = (const int*)d_in[1];
    const int*   src   = ei;
    const int*   dst   = ei + E;
    const int*   batch = (const int*)d_in[2];
    const float* W1    = (const float*)d_in[3];
    const float* b1    = (const float*)d_in[4];
    const float* W2    = (const float*)d_in[5];
    const float* b2    = (const float*)d_in[6];
    float* out = (float*)d_out;

    char* p = (char*)d_ws;
    auto carve = [&](size_t bytes) {
        void* r = (void*)p;
        p += (bytes + 63) & ~(size_t)63;
        return r;
    };
    int*   bcnt   = (int*)carve(NB_MAX * 4);
    int*   boffs  = (int*)carve((NB_MAX + 1) * 4);
    int*   bcur   = (int*)carve(NB_MAX * 4);
    int*   packed = (int*)carve((size_t)E * 4);
    int*   sidx2  = (int*)carve((size_t)E * 4);
    int*   noffs  = (int*)carve((size_t)(n + 1) * 4);
    float* dinv   = (float*)carve((size_t)n * 4);
    float* hs     = (float*)carve((size_t)n * 16 * 4);
    float* hw     = (float*)carve((size_t)n * 4);

    int nb = (n + 255) >> 8;

    hipMemsetAsync(d_out, 0, (size_t)out_size * sizeof(float), stream);
    hipMemsetAsync(bcnt, 0, NB_MAX * sizeof(int), stream);

    k_hist<<<256, 256, 0, stream>>>(dst, bcnt, E, nb);
    k_bscan<<<1, NB_MAX, 0, stream>>>(bcnt, boffs, bcur, nb);
    k_scatter<<<(E + CHUNK - 1) / CHUNK, 512, 0, stream>>>(src, dst, bcur, packed, E, nb);
    k_sort2<<<nb, 256, 0, stream>>>(packed, boffs, sidx2, noffs, dinv, n, E);
    k_gemm1<<<(n + 15) / 16, 256, 0, stream>>>(x, W1, dinv, hs, n);
    k_agg1<<<((size_t)n * 4 + 255) / 256, 256, 0, stream>>>((const float4*)hs, noffs, sidx2, dinv, b1, W2, hw, n);
    k_agg2<<<nb, 256, 0, stream>>>(hw, noffs, sidx2, dinv, b2, batch, out, n);
}

// Round 5
// 201.883 us; speedup vs baseline: 15.1439x; 1.1684x over previous
//
#include <hip/hip_runtime.h>

#define NB_MAX 512      // max buckets (n <= 131072)
#define CHUNK  8192     // edges per scatter block

// ---- bucket histogram: bcnt[b] = #edges with dst>>8 == b ----
__global__ __launch_bounds__(256) void k_hist(const int* __restrict__ dst,
                                              int* __restrict__ bcnt, int E, int nb) {
    __shared__ int h[NB_MAX];
    int t = threadIdx.x;
    for (int q = t; q < NB_MAX; q += 256) h[q] = 0;
    __syncthreads();
    for (int e = blockIdx.x * 256 + t; e < E; e += gridDim.x * 256)
        atomicAdd(&h[dst[e] >> 8], 1);
    __syncthreads();
    for (int q = t; q < nb; q += 256)
        if (h[q]) atomicAdd(&bcnt[q], h[q]);
}

// ---- single-block exclusive scan of bucket counts ----
__global__ __launch_bounds__(NB_MAX) void k_bscan(const int* __restrict__ bcnt,
                                                  int* __restrict__ boffs,
                                                  int* __restrict__ bcur, int nb) {
    __shared__ int s[NB_MAX];
    int t = threadIdx.x;
    int v = (t < nb) ? bcnt[t] : 0;
    s[t] = v;
    __syncthreads();
    for (int o = 1; o < NB_MAX; o <<= 1) {
        int u = (t >= o) ? s[t - o] : 0;
        __syncthreads();
        s[t] += u;
        __syncthreads();
    }
    if (t < nb) {
        boffs[t + 1] = s[t];
        bcur[t] = s[t] - v;
        if (t == 0) boffs[0] = 0;
    }
}

// ---- pass 1: scatter edges into bucket-contiguous packed = src | dl<<24 ----
__global__ __launch_bounds__(512) void k_scatter(const int* __restrict__ src,
                                                 const int* __restrict__ dst,
                                                 int* __restrict__ bcur,
                                                 int* __restrict__ packed,
                                                 int E, int nb) {
    __shared__ int lh[NB_MAX];
    __shared__ int lbase[NB_MAX];
    int t = threadIdx.x;
    int e0 = blockIdx.x * CHUNK;
    int e1 = min(e0 + CHUNK, E);
    for (int q = t; q < NB_MAX; q += 512) lh[q] = 0;
    __syncthreads();
    for (int e = e0 + t; e < e1; e += 512) atomicAdd(&lh[dst[e] >> 8], 1);
    __syncthreads();
    for (int q = t; q < nb; q += 512) {
        int c = lh[q];
        lbase[q] = c ? atomicAdd(&bcur[q], c) : 0;
        lh[q] = 0;
    }
    __syncthreads();
    for (int e = e0 + t; e < e1; e += 512) {
        int d = dst[e];
        int b = d >> 8;
        int r = atomicAdd(&lh[b], 1);
        packed[lbase[b] + r] = src[e] | ((d & 255) << 24);
    }
}

// ---- pass 2: within-bucket sort by dst -> sidx2, per-node CSR noffs, dinv ----
__global__ __launch_bounds__(512) void k_sort2(const int* __restrict__ packed,
                                               const int* __restrict__ boffs,
                                               int* __restrict__ sidx2,
                                               int* __restrict__ noffs,
                                               float* __restrict__ dinv,
                                               int n, int E) {
    __shared__ int hist[256];
    __shared__ int scan[256];
    __shared__ int curs[256];
    int t = threadIdx.x, b = blockIdx.x;
    if (t < 256) hist[t] = 0;
    __syncthreads();
    int e0 = boffs[b], e1 = boffs[b + 1];
    for (int e = e0 + t; e < e1; e += 512)
        atomicAdd(&hist[(unsigned)packed[e] >> 24], 1);
    __syncthreads();
    int v = 0;
    if (t < 256) { v = hist[t]; scan[t] = v; }
    __syncthreads();
    for (int o = 1; o < 256; o <<= 1) {
        int u = (t < 256 && t >= o) ? scan[t - o] : 0;
        __syncthreads();
        if (t < 256) scan[t] += u;
        __syncthreads();
    }
    if (t < 256) {
        int ex = scan[t] - v;               // exclusive prefix within bucket
        curs[t] = ex;
        int node = (b << 8) + t;
        if (node < n) {
            noffs[node] = e0 + ex;
            dinv[node] = rsqrtf((float)v + 1.0f);
            if (node == n - 1) noffs[n] = E;
        }
    }
    __syncthreads();
    for (int e = e0 + t; e < e1; e += 512) {
        int p = packed[e];
        int dl = (int)((unsigned)p >> 24);
        int r = atomicAdd(&curs[dl], 1);
        sidx2[e0 + r] = p & 0xFFFFFF;
    }
}

// ---- hs = (x @ W1) * dinv  (N x 128 @ 128 x 16) ----
__global__ __launch_bounds__(256) void k_gemm1(const float* __restrict__ x,
                                               const float* __restrict__ W1,
                                               const float* __restrict__ dinv,
                                               float* __restrict__ hs, int n) {
    __shared__ float sW[128 * 16];
    __shared__ float sX[16 * 128];
    int t = threadIdx.x;
    for (int q = t; q < 2048; q += 256) sW[q] = W1[q];
    int node0 = blockIdx.x * 16;
    const float* xp = x + (size_t)node0 * 128;
    int nrem = n - node0;
    int nload = (nrem >= 16 ? 16 : nrem) * 128;
    for (int q = t; q < nload; q += 256) sX[q] = xp[q];
    __syncthreads();
    int local = t >> 4;
    int col = t & 15;
    int node = node0 + local;
    if (node >= n) return;
    float acc = 0.f;
#pragma unroll 8
    for (int k = 0; k < 128; k++) acc += sX[local * 128 + k] * sW[k * 16 + col];
    hs[(size_t)node * 16 + col] = acc * dinv[node];
}

// ---- layer-1: CSR register-accumulate (4 lanes/node, float4 each), no atomics ----
__global__ __launch_bounds__(256) void k_agg1(const float4* __restrict__ hs4,
                                              const int* __restrict__ noffs,
                                              const int* __restrict__ sidx2,
                                              const float* __restrict__ dinv,
                                              const float* __restrict__ b1,
                                              const float* __restrict__ W2,
                                              float* __restrict__ hw, int n) {
    int tid = blockIdx.x * 256 + threadIdx.x;
    int node = tid >> 2, q = tid & 3;
    if (node >= n) return;
    int e0 = noffs[node], e1 = noffs[node + 1];
    float4 acc = hs4[(size_t)node * 4 + q];       // self-loop term (pre-scaled)
    int e = e0;
    for (; e + 1 < e1; e += 2) {                  // 2 gathers in flight
        int s0 = sidx2[e], s1 = sidx2[e + 1];
        float4 a = hs4[(size_t)s0 * 4 + q];
        float4 c = hs4[(size_t)s1 * 4 + q];
        acc.x += a.x + c.x;
        acc.y += a.y + c.y;
        acc.z += a.z + c.z;
        acc.w += a.w + c.w;
    }
    if (e < e1) {
        float4 a = hs4[(size_t)sidx2[e] * 4 + q];
        acc.x += a.x; acc.y += a.y; acc.z += a.z; acc.w += a.w;
    }
    float di = dinv[node];
    const float4 bb = ((const float4*)b1)[q];
    const float4 ww = ((const float4*)W2)[q];
    float r = fmaxf(di * acc.x + bb.x, 0.f) * ww.x
            + fmaxf(di * acc.y + bb.y, 0.f) * ww.y
            + fmaxf(di * acc.z + bb.z, 0.f) * ww.z
            + fmaxf(di * acc.w + bb.w, 0.f) * ww.w;
    r += __shfl_down(r, 2, 4);
    r += __shfl_down(r, 1, 4);
    if (q == 0) hw[node] = r * di;                // pre-scaled for layer 2
}

// ---- layer-2: CSR register-accumulate + b2 + segmented pool (batch sorted) ----
__global__ __launch_bounds__(256) void k_agg2(const float* __restrict__ hw,
                                              const int* __restrict__ noffs,
                                              const int* __restrict__ sidx2,
                                              const float* __restrict__ dinv,
                                              const float* __restrict__ b2,
                                              const int* __restrict__ batch,
                                              float* __restrict__ out, int n) {
    __shared__ float v[256];
    __shared__ int g[256];
    int t = threadIdx.x;
    int i = blockIdx.x * 256 + t;
    float val = 0.f;
    int gid = -1;
    if (i < n) {
        float acc = hw[i];                        // self-loop
        int e0 = noffs[i], e1 = noffs[i + 1];
        int e = e0;
        for (; e + 1 < e1; e += 2) {
            float a = hw[sidx2[e]];
            float c = hw[sidx2[e + 1]];
            acc += a + c;
        }
        if (e < e1) acc += hw[sidx2[e]];
        val = dinv[i] * acc + b2[0];
        gid = batch[i];
    }
    v[t] = val;
    g[t] = gid;
    __syncthreads();
    if (gid >= 0 && (t == 0 || g[t - 1] != gid)) {
        float s = val;
        for (int q = t + 1; q < 256 && g[q] == gid; q++) s += v[q];
        atomicAdd(&out[gid], s);
    }
}

extern "C" void kernel_launch(void* const* d_in, const int* in_sizes, int n_in,
                              void* d_out, int out_size, void* d_ws, size_t ws_size,
                              hipStream_t stream) {
    int n = in_sizes[0] / 128;
    int E = in_sizes[1] / 2;
    const float* x     = (const float*)d_in[0];
    const int*   ei    = (const int*)d_in[1];
    const int*   src   = ei;
    const int*   dst   = ei + E;
    const int*   batch = (const int*)d_in[2];
    const float* W1    = (const float*)d_in[3];
    const float* b1    = (const float*)d_in[4];
    const float* W2    = (const float*)d_in[5];
    const float* b2    = (const float*)d_in[6];
    float* out = (float*)d_out;

    char* p = (char*)d_ws;
    auto carve = [&](size_t bytes) {
        void* r = (void*)p;
        p += (bytes + 63) & ~(size_t)63;
        return r;
    };
    int*   bcnt   = (int*)carve(NB_MAX * 4);
    int*   boffs  = (int*)carve((NB_MAX + 1) * 4);
    int*   bcur   = (int*)carve(NB_MAX * 4);
    int*   packed = (int*)carve((size_t)E * 4);
    int*   sidx2  = (int*)carve((size_t)E * 4);
    int*   noffs  = (int*)carve((size_t)(n + 1) * 4);
    float* dinv   = (float*)carve((size_t)n * 4);
    float* hs     = (float*)carve((size_t)n * 16 * 4);
    float* hw     = (float*)carve((size_t)n * 4);

    int nb = (n + 255) >> 8;

    hipMemsetAsync(d_out, 0, (size_t)out_size * sizeof(float), stream);
    hipMemsetAsync(bcnt, 0, NB_MAX * sizeof(int), stream);

    k_hist<<<512, 256, 0, stream>>>(dst, bcnt, E, nb);
    k_bscan<<<1, NB_MAX, 0, stream>>>(bcnt, boffs, bcur, nb);
    k_scatter<<<(E + CHUNK - 1) / CHUNK, 512, 0, stream>>>(src, dst, bcur, packed, E, nb);
    k_sort2<<<nb, 512, 0, stream>>>(packed, boffs, sidx2, noffs, dinv, n, E);
    k_gemm1<<<(n + 15) / 16, 256, 0, stream>>>(x, W1, dinv, hs, n);
    k_agg1<<<((size_t)n * 4 + 255) / 256, 256, 0, stream>>>((const float4*)hs, noffs, sidx2, dinv, b1, W2, hw, n);
    k_agg2<<<nb, 256, 0, stream>>>(hw, noffs, sidx2, dinv, b2, batch, out, n);
}

// Round 6
// 181.594 us; speedup vs baseline: 16.8358x; 1.1117x over previous
//
#include <hip/hip_runtime.h>

#define NB_MAX 512      // max buckets (n <= 131072)
#define CHUNK  8192     // edges per scatter block

__device__ inline unsigned short f2bf(float f) {   // round-to-nearest-even bf16
    unsigned u = __float_as_uint(f);
    u += 0x7FFFu + ((u >> 16) & 1u);
    return (unsigned short)(u >> 16);
}

// ---- bucket histogram: bcnt[b] = #edges with dst>>8 == b ----
__global__ __launch_bounds__(256) void k_hist(const int* __restrict__ dst,
                                              int* __restrict__ bcnt, int E, int nb) {
    __shared__ int h[NB_MAX];
    int t = threadIdx.x;
    for (int q = t; q < NB_MAX; q += 256) h[q] = 0;
    __syncthreads();
    for (int e = blockIdx.x * 256 + t; e < E; e += gridDim.x * 256)
        atomicAdd(&h[dst[e] >> 8], 1);
    __syncthreads();
    for (int q = t; q < nb; q += 256)
        if (h[q]) atomicAdd(&bcnt[q], h[q]);
}

// ---- single-block exclusive scan of bucket counts ----
__global__ __launch_bounds__(NB_MAX) void k_bscan(const int* __restrict__ bcnt,
                                                  int* __restrict__ boffs,
                                                  int* __restrict__ bcur, int nb) {
    __shared__ int s[NB_MAX];
    int t = threadIdx.x;
    int v = (t < nb) ? bcnt[t] : 0;
    s[t] = v;
    __syncthreads();
    for (int o = 1; o < NB_MAX; o <<= 1) {
        int u = (t >= o) ? s[t - o] : 0;
        __syncthreads();
        s[t] += u;
        __syncthreads();
    }
    if (t < nb) {
        boffs[t + 1] = s[t];
        bcur[t] = s[t] - v;
        if (t == 0) boffs[0] = 0;
    }
}

// ---- pass 1: LDS bucket-sort each chunk, then coalesced run writes ----
// packed = src | (dst&255)<<24, grouped by bucket (dst>>8)
__global__ __launch_bounds__(512) void k_scatter(const int* __restrict__ src,
                                                 const int* __restrict__ dst,
                                                 int* __restrict__ bcur,
                                                 int* __restrict__ packed,
                                                 int E, int nb) {
    __shared__ int lh[NB_MAX];          // hist -> absolute LDS cursor
    __shared__ int lscan[NB_MAX];       // inclusive scan workspace
    __shared__ int ldelta[NB_MAX];      // global_base - local_base per bucket
    __shared__ int sorted[CHUNK];
    __shared__ unsigned short sbkt[CHUNK];
    int t = threadIdx.x;
    int e0 = blockIdx.x * CHUNK;
    int e1 = min(e0 + CHUNK, E);
    int cnt = e1 - e0;
    lh[t] = 0;
    __syncthreads();
    for (int e = e0 + t; e < e1; e += 512) atomicAdd(&lh[dst[e] >> 8], 1);
    __syncthreads();
    int v = lh[t];
    lscan[t] = v;
    __syncthreads();
    for (int o = 1; o < 512; o <<= 1) {
        int u = (t >= o) ? lscan[t - o] : 0;
        __syncthreads();
        lscan[t] += u;
        __syncthreads();
    }
    int ex = lscan[t] - v;                          // exclusive prefix
    int gbase = v ? atomicAdd(&bcur[t], v) : 0;     // one reservation per (block,bucket)
    lh[t] = ex;                                     // reuse as LDS write cursor
    ldelta[t] = gbase - ex;
    __syncthreads();
    for (int e = e0 + t; e < e1; e += 512) {
        int d = dst[e];
        int b = d >> 8;
        int r = atomicAdd(&lh[b], 1);
        sorted[r] = src[e] | ((d & 255) << 24);
        sbkt[r] = (unsigned short)b;
    }
    __syncthreads();
    for (int i = t; i < cnt; i += 512)              // coalesced run writes
        packed[i + ldelta[sbkt[i]]] = sorted[i];
}

// ---- pass 2: within-bucket sort by dst -> sidx2, per-node CSR noffs, dinv ----
__global__ __launch_bounds__(512) void k_sort2(const int* __restrict__ packed,
                                               const int* __restrict__ boffs,
                                               int* __restrict__ sidx2,
                                               int* __restrict__ noffs,
                                               float* __restrict__ dinv,
                                               int n, int E) {
    __shared__ int hist[256];
    __shared__ int scan[256];
    __shared__ int curs[256];
    int t = threadIdx.x, b = blockIdx.x;
    if (t < 256) hist[t] = 0;
    __syncthreads();
    int e0 = boffs[b], e1 = boffs[b + 1];
    for (int e = e0 + t; e < e1; e += 512)
        atomicAdd(&hist[(unsigned)packed[e] >> 24], 1);
    __syncthreads();
    int v = 0;
    if (t < 256) { v = hist[t]; scan[t] = v; }
    __syncthreads();
    for (int o = 1; o < 256; o <<= 1) {
        int u = (t < 256 && t >= o) ? scan[t - o] : 0;
        __syncthreads();
        if (t < 256) scan[t] += u;
        __syncthreads();
    }
    if (t < 256) {
        int ex = scan[t] - v;
        curs[t] = ex;
        int node = (b << 8) + t;
        if (node < n) {
            noffs[node] = e0 + ex;
            dinv[node] = rsqrtf((float)v + 1.0f);
            if (node == n - 1) noffs[n] = E;
        }
    }
    __syncthreads();
    for (int e = e0 + t; e < e1; e += 512) {
        int p = packed[e];
        int dl = (int)((unsigned)p >> 24);
        int r = atomicAdd(&curs[dl], 1);
        sidx2[e0 + r] = p & 0xFFFFFF;
    }
}

// ---- hs = bf16((x @ W1) * dinv)  (N x 128 @ 128 x 16) ----
__global__ __launch_bounds__(256) void k_gemm1(const float* __restrict__ x,
                                               const float* __restrict__ W1,
                                               const float* __restrict__ dinv,
                                               unsigned short* __restrict__ hs, int n) {
    __shared__ float sW[128 * 16];
    __shared__ float sX[16 * 128];
    int t = threadIdx.x;
    for (int q = t; q < 2048; q += 256) sW[q] = W1[q];
    int node0 = blockIdx.x * 16;
    const float* xp = x + (size_t)node0 * 128;
    int nrem = n - node0;
    int nload = (nrem >= 16 ? 16 : nrem) * 128;
    for (int q = t; q < nload; q += 256) sX[q] = xp[q];
    __syncthreads();
    int local = t >> 4;
    int col = t & 15;
    int node = node0 + local;
    if (node >= n) return;
    float acc = 0.f;
#pragma unroll 8
    for (int k = 0; k < 128; k++) acc += sX[local * 128 + k] * sW[k * 16 + col];
    hs[(size_t)node * 16 + col] = f2bf(acc * dinv[node]);
}

// ---- layer-1: CSR register-accumulate, 2 lanes/node, bf16 rows (32B) ----
__global__ __launch_bounds__(256) void k_agg1(const uint4* __restrict__ hs4,
                                              const int* __restrict__ noffs,
                                              const int* __restrict__ sidx2,
                                              const float* __restrict__ dinv,
                                              const float* __restrict__ b1,
                                              const float* __restrict__ W2,
                                              float* __restrict__ hw, int n) {
    int tid = blockIdx.x * 256 + threadIdx.x;
    int node = tid >> 1, q = tid & 1;          // 2 lanes per node, 16B each
    if (node >= n) return;
    float acc[8];
    uint4 u0 = hs4[(size_t)node * 2 + q];      // self-loop row (pre-scaled)
    acc[0] = __uint_as_float(u0.x << 16);
    acc[1] = __uint_as_float(u0.x & 0xFFFF0000u);
    acc[2] = __uint_as_float(u0.y << 16);
    acc[3] = __uint_as_float(u0.y & 0xFFFF0000u);
    acc[4] = __uint_as_float(u0.z << 16);
    acc[5] = __uint_as_float(u0.z & 0xFFFF0000u);
    acc[6] = __uint_as_float(u0.w << 16);
    acc[7] = __uint_as_float(u0.w & 0xFFFF0000u);
    int e0 = noffs[node], e1 = noffs[node + 1];
    int e = e0;
    for (; e + 1 < e1; e += 2) {               // 2 gathers in flight
        int s0 = sidx2[e], s1 = sidx2[e + 1];
        uint4 a = hs4[(size_t)s0 * 2 + q];
        uint4 c = hs4[(size_t)s1 * 2 + q];
        acc[0] += __uint_as_float(a.x << 16) + __uint_as_float(c.x << 16);
        acc[1] += __uint_as_float(a.x & 0xFFFF0000u) + __uint_as_float(c.x & 0xFFFF0000u);
        acc[2] += __uint_as_float(a.y << 16) + __uint_as_float(c.y << 16);
        acc[3] += __uint_as_float(a.y & 0xFFFF0000u) + __uint_as_float(c.y & 0xFFFF0000u);
        acc[4] += __uint_as_float(a.z << 16) + __uint_as_float(c.z << 16);
        acc[5] += __uint_as_float(a.z & 0xFFFF0000u) + __uint_as_float(c.z & 0xFFFF0000u);
        acc[6] += __uint_as_float(a.w << 16) + __uint_as_float(c.w << 16);
        acc[7] += __uint_as_float(a.w & 0xFFFF0000u) + __uint_as_float(c.w & 0xFFFF0000u);
    }
    if (e < e1) {
        uint4 a = hs4[(size_t)sidx2[e] * 2 + q];
        acc[0] += __uint_as_float(a.x << 16);
        acc[1] += __uint_as_float(a.x & 0xFFFF0000u);
        acc[2] += __uint_as_float(a.y << 16);
        acc[3] += __uint_as_float(a.y & 0xFFFF0000u);
        acc[4] += __uint_as_float(a.z << 16);
        acc[5] += __uint_as_float(a.z & 0xFFFF0000u);
        acc[6] += __uint_as_float(a.w << 16);
        acc[7] += __uint_as_float(a.w & 0xFFFF0000u);
    }
    float di = dinv[node];
    int base = q * 8;
    float r = 0.f;
#pragma unroll
    for (int j = 0; j < 8; j++)
        r += fmaxf(di * acc[j] + b1[base + j], 0.f) * W2[base + j];
    r += __shfl_down(r, 1, 2);
    if (q == 0) hw[node] = r * di;              // pre-scaled for layer 2
}

// ---- layer-2: CSR register-accumulate + b2 + segmented pool (batch sorted) ----
__global__ __launch_bounds__(256) void k_agg2(const float* __restrict__ hw,
                                              const int* __restrict__ noffs,
                                              const int* __restrict__ sidx2,
                                              const float* __restrict__ dinv,
                                              const float* __restrict__ b2,
                                              const int* __restrict__ batch,
                                              float* __restrict__ out, int n) {
    __shared__ float v[256];
    __shared__ int g[256];
    int t = threadIdx.x;
    int i = blockIdx.x * 256 + t;
    float val = 0.f;
    int gid = -1;
    if (i < n) {
        float acc = hw[i];                      // self-loop
        int e0 = noffs[i], e1 = noffs[i + 1];
        int e = e0;
        for (; e + 1 < e1; e += 2) {
            float a = hw[sidx2[e]];
            float c = hw[sidx2[e + 1]];
            acc += a + c;
        }
        if (e < e1) acc += hw[sidx2[e]];
        val = dinv[i] * acc + b2[0];
        gid = batch[i];
    }
    v[t] = val;
    g[t] = gid;
    __syncthreads();
    if (gid >= 0 && (t == 0 || g[t - 1] != gid)) {
        float s = val;
        for (int q = t + 1; q < 256 && g[q] == gid; q++) s += v[q];
        atomicAdd(&out[gid], s);
    }
}

extern "C" void kernel_launch(void* const* d_in, const int* in_sizes, int n_in,
                              void* d_out, int out_size, void* d_ws, size_t ws_size,
                              hipStream_t stream) {
    int n = in_sizes[0] / 128;
    int E = in_sizes[1] / 2;
    const float* x     = (const float*)d_in[0];
    const int*   ei    = (const int*)d_in[1];
    const int*   src   = ei;
    const int*   dst   = ei + E;
    const int*   batch = (const int*)d_in[2];
    const float* W1    = (const float*)d_in[3];
    const float* b1    = (const float*)d_in[4];
    const float* W2    = (const float*)d_in[5];
    const float* b2    = (const float*)d_in[6];
    float* out = (float*)d_out;

    char* p = (char*)d_ws;
    auto carve = [&](size_t bytes) {
        void* r = (void*)p;
        p += (bytes + 63) & ~(size_t)63;
        return r;
    };
    int*            bcnt   = (int*)carve(NB_MAX * 4);
    int*            boffs  = (int*)carve((NB_MAX + 1) * 4);
    int*            bcur   = (int*)carve(NB_MAX * 4);
    int*            packed = (int*)carve((size_t)E * 4);
    int*            sidx2  = (int*)carve((size_t)E * 4);
    int*            noffs  = (int*)carve((size_t)(n + 1) * 4);
    float*          dinv   = (float*)carve((size_t)n * 4);
    unsigned short* hs     = (unsigned short*)carve((size_t)n * 16 * 2);
    float*          hw     = (float*)carve((size_t)n * 4);

    int nb = (n + 255) >> 8;

    hipMemsetAsync(d_out, 0, (size_t)out_size * sizeof(float), stream);
    hipMemsetAsync(bcnt, 0, NB_MAX * sizeof(int), stream);

    k_hist<<<512, 256, 0, stream>>>(dst, bcnt, E, nb);
    k_bscan<<<1, NB_MAX, 0, stream>>>(bcnt, boffs, bcur, nb);
    k_scatter<<<(E + CHUNK - 1) / CHUNK, 512, 0, stream>>>(src, dst, bcur, packed, E, nb);
    k_sort2<<<nb, 512, 0, stream>>>(packed, boffs, sidx2, noffs, dinv, n, E);
    k_gemm1<<<(n + 15) / 16, 256, 0, stream>>>(x, W1, dinv, hs, n);
    k_agg1<<<((size_t)n * 2 + 255) / 256, 256, 0, stream>>>((const uint4*)hs, noffs, sidx2, dinv, b1, W2, hw, n);
    k_agg2<<<nb, 256, 0, stream>>>(hw, noffs, sidx2, dinv, b2, batch, out, n);
}

// Round 7
// 171.932 us; speedup vs baseline: 17.7820x; 1.0562x over previous
//
#include <hip/hip_runtime.h>

#define NB_MAX 512      // max buckets (n <= 131072)
#define CHUNK  8192     // edges per scatter block
#define CAPB   16384    // slots per bucket region (mean ~8184, +90 sigma headroom)

__device__ inline unsigned short f2bf(float f) {   // round-to-nearest-even bf16
    unsigned u = __float_as_uint(f);
    u += 0x7FFFu + ((u >> 16) & 1u);
    return (unsigned short)(u >> 16);
}

// ---- pass 1: LDS bucket-sort each chunk, reserve space in fixed bucket
//      regions via one atomic per (block,bucket), coalesced run writes.
//      packed[b*CAPB .. b*CAPB+bcnt[b]) = src | (dst&255)<<24 for bucket b ----
__global__ __launch_bounds__(512) void k_scatter(const int* __restrict__ src,
                                                 const int* __restrict__ dst,
                                                 int* __restrict__ bcnt,
                                                 int* __restrict__ packed,
                                                 int E) {
    __shared__ int lh[NB_MAX];          // hist -> LDS write cursor
    __shared__ int lscan[NB_MAX];
    __shared__ int ldelta[NB_MAX];      // (region base + gbase) - local exclusive base
    __shared__ int sorted[CHUNK];
    __shared__ unsigned short sbkt[CHUNK];
    int t = threadIdx.x;
    int e0 = blockIdx.x * CHUNK;
    int e1 = min(e0 + CHUNK, E);
    int cnt = e1 - e0;
    lh[t] = 0;
    __syncthreads();
    for (int e = e0 + t; e < e1; e += 512) atomicAdd(&lh[dst[e] >> 8], 1);
    __syncthreads();
    int v = lh[t];
    lscan[t] = v;
    __syncthreads();
    for (int o = 1; o < 512; o <<= 1) {
        int u = (t >= o) ? lscan[t - o] : 0;
        __syncthreads();
        lscan[t] += u;
        __syncthreads();
    }
    int ex = lscan[t] - v;                          // exclusive prefix in chunk
    int gbase = v ? atomicAdd(&bcnt[t], v) : 0;     // reservation in bucket region
    lh[t] = ex;                                     // LDS sort cursor
    ldelta[t] = t * CAPB + gbase - ex;
    __syncthreads();
    for (int e = e0 + t; e < e1; e += 512) {
        int d = dst[e];
        int b = d >> 8;
        int r = atomicAdd(&lh[b], 1);
        sorted[r] = src[e] | ((d & 255) << 24);
        sbkt[r] = (unsigned short)b;
    }
    __syncthreads();
    for (int i = t; i < cnt; i += 512)              // coalesced run writes
        packed[i + ldelta[sbkt[i]]] = sorted[i];
}

// ---- per-bucket degree hist + scan -> dinv, noffs (sidx2 coords), ndeg ----
__global__ __launch_bounds__(512) void k_dinv(const int* __restrict__ packed,
                                              const int* __restrict__ bcnt,
                                              float* __restrict__ dinv,
                                              int* __restrict__ noffs,
                                              int* __restrict__ ndeg, int n) {
    __shared__ int hist[256];
    __shared__ int scan[256];
    int t = threadIdx.x, b = blockIdx.x;
    if (t < 256) hist[t] = 0;
    __syncthreads();
    int seg0 = b * CAPB, cnt = bcnt[b];
    for (int e = t; e < cnt; e += 512)
        atomicAdd(&hist[(unsigned)packed[seg0 + e] >> 24], 1);
    __syncthreads();
    int v = 0;
    if (t < 256) { v = hist[t]; scan[t] = v; }
    __syncthreads();
    for (int o = 1; o < 256; o <<= 1) {
        int u = (t < 256 && t >= o) ? scan[t - o] : 0;
        __syncthreads();
        if (t < 256) scan[t] += u;
        __syncthreads();
    }
    if (t < 256) {
        int node = (b << 8) + t;
        if (node < n) {
            noffs[node] = seg0 + (scan[t] - v);
            ndeg[node] = v;
            dinv[node] = rsqrtf((float)v + 1.0f);
        }
    }
}

// ---- hs = bf16((x @ W1) * dinv)  (N x 128 @ 128 x 16) ----
__global__ __launch_bounds__(256) void k_gemm1(const float* __restrict__ x,
                                               const float* __restrict__ W1,
                                               const float* __restrict__ dinv,
                                               unsigned short* __restrict__ hs, int n) {
    __shared__ float sW[128 * 16];
    __shared__ float sX[16 * 128];
    int t = threadIdx.x;
    for (int q = t; q < 2048; q += 256) sW[q] = W1[q];
    int node0 = blockIdx.x * 16;
    const float* xp = x + (size_t)node0 * 128;
    int nrem = n - node0;
    int nload = (nrem >= 16 ? 16 : nrem) * 128;
    for (int q = t; q < nload; q += 256) sX[q] = xp[q];
    __syncthreads();
    int local = t >> 4;
    int col = t & 15;
    int node = node0 + local;
    if (node >= n) return;
    float acc = 0.f;
#pragma unroll 8
    for (int k = 0; k < 128; k++) acc += sX[local * 128 + k] * sW[k * 16 + col];
    hs[(size_t)node * 16 + col] = f2bf(acc * dinv[node]);
}

// ---- fused: per-bucket sidx2 scatter (stays in this XCD's L2) + layer-1
//      CSR register-accumulate (2 lanes/node, bf16 rows) -> hw ----
__global__ __launch_bounds__(512) void k_fused1(const int* __restrict__ packed,
                                                const int* __restrict__ bcnt,
                                                const int* __restrict__ noffs,
                                                const int* __restrict__ ndeg,
                                                int* __restrict__ sidx2,
                                                const uint4* __restrict__ hs4,
                                                const float* __restrict__ dinv,
                                                const float* __restrict__ b1,
                                                const float* __restrict__ W2,
                                                float* __restrict__ hw, int n) {
    __shared__ int curs[256];
    int t = threadIdx.x, b = blockIdx.x;
    int seg0 = b * CAPB, cnt = bcnt[b];
    if (t < 256) {
        int node = (b << 8) + t;
        curs[t] = (node < n) ? noffs[node] : 0;
    }
    __syncthreads();
    for (int e = t; e < cnt; e += 512) {            // dst-sort into sidx2 region
        int p = packed[seg0 + e];
        int dl = (int)((unsigned)p >> 24);
        int r = atomicAdd(&curs[dl], 1);
        sidx2[r] = p & 0xFFFFFF;
    }
    __syncthreads();
    int node = (b << 8) + (t >> 1), q = t & 1;      // 2 lanes/node, 16B each
    if (node >= n) return;
    float acc[8];
    uint4 u0 = hs4[(size_t)node * 2 + q];           // self-loop row (pre-scaled)
    acc[0] = __uint_as_float(u0.x << 16);
    acc[1] = __uint_as_float(u0.x & 0xFFFF0000u);
    acc[2] = __uint_as_float(u0.y << 16);
    acc[3] = __uint_as_float(u0.y & 0xFFFF0000u);
    acc[4] = __uint_as_float(u0.z << 16);
    acc[5] = __uint_as_float(u0.z & 0xFFFF0000u);
    acc[6] = __uint_as_float(u0.w << 16);
    acc[7] = __uint_as_float(u0.w & 0xFFFF0000u);
    int e0 = noffs[node], e1 = e0 + ndeg[node];
    int e = e0;
    for (; e + 1 < e1; e += 2) {                    // 2 gathers in flight
        int s0 = sidx2[e], s1 = sidx2[e + 1];
        uint4 a = hs4[(size_t)s0 * 2 + q];
        uint4 c = hs4[(size_t)s1 * 2 + q];
        acc[0] += __uint_as_float(a.x << 16) + __uint_as_float(c.x << 16);
        acc[1] += __uint_as_float(a.x & 0xFFFF0000u) + __uint_as_float(c.x & 0xFFFF0000u);
        acc[2] += __uint_as_float(a.y << 16) + __uint_as_float(c.y << 16);
        acc[3] += __uint_as_float(a.y & 0xFFFF0000u) + __uint_as_float(c.y & 0xFFFF0000u);
        acc[4] += __uint_as_float(a.z << 16) + __uint_as_float(c.z << 16);
        acc[5] += __uint_as_float(a.z & 0xFFFF0000u) + __uint_as_float(c.z & 0xFFFF0000u);
        acc[6] += __uint_as_float(a.w << 16) + __uint_as_float(c.w << 16);
        acc[7] += __uint_as_float(a.w & 0xFFFF0000u) + __uint_as_float(c.w & 0xFFFF0000u);
    }
    if (e < e1) {
        uint4 a = hs4[(size_t)sidx2[e] * 2 + q];
        acc[0] += __uint_as_float(a.x << 16);
        acc[1] += __uint_as_float(a.x & 0xFFFF0000u);
        acc[2] += __uint_as_float(a.y << 16);
        acc[3] += __uint_as_float(a.y & 0xFFFF0000u);
        acc[4] += __uint_as_float(a.z << 16);
        acc[5] += __uint_as_float(a.z & 0xFFFF0000u);
        acc[6] += __uint_as_float(a.w << 16);
        acc[7] += __uint_as_float(a.w & 0xFFFF0000u);
    }
    float di = dinv[node];
    int base = q * 8;
    float r = 0.f;
#pragma unroll
    for (int j = 0; j < 8; j++)
        r += fmaxf(di * acc[j] + b1[base + j], 0.f) * W2[base + j];
    r += __shfl_down(r, 1, 2);
    if (q == 0) hw[node] = r * di;                  // pre-scaled for layer 2
}

// ---- layer-2: CSR register-accumulate + b2 + segmented pool (batch sorted) ----
__global__ __launch_bounds__(256) void k_agg2(const float* __restrict__ hw,
                                              const int* __restrict__ noffs,
                                              const int* __restrict__ ndeg,
                                              const int* __restrict__ sidx2,
                                              const float* __restrict__ dinv,
                                              const float* __restrict__ b2,
                                              const int* __restrict__ batch,
                                              float* __restrict__ out, int n) {
    __shared__ float v[256];
    __shared__ int g[256];
    int t = threadIdx.x;
    int i = blockIdx.x * 256 + t;
    float val = 0.f;
    int gid = -1;
    if (i < n) {
        float acc = hw[i];                          // self-loop
        int e0 = noffs[i], e1 = e0 + ndeg[i];
        int e = e0;
        for (; e + 1 < e1; e += 2) {
            float a = hw[sidx2[e]];
            float c = hw[sidx2[e + 1]];
            acc += a + c;
        }
        if (e < e1) acc += hw[sidx2[e]];
        val = dinv[i] * acc + b2[0];
        gid = batch[i];
    }
    v[t] = val;
    g[t] = gid;
    __syncthreads();
    if (gid >= 0 && (t == 0 || g[t - 1] != gid)) {
        float s = val;
        for (int q = t + 1; q < 256 && g[q] == gid; q++) s += v[q];
        atomicAdd(&out[gid], s);
    }
}

extern "C" void kernel_launch(void* const* d_in, const int* in_sizes, int n_in,
                              void* d_out, int out_size, void* d_ws, size_t ws_size,
                              hipStream_t stream) {
    int n = in_sizes[0] / 128;
    int E = in_sizes[1] / 2;
    const float* x     = (const float*)d_in[0];
    const int*   ei    = (const int*)d_in[1];
    const int*   src   = ei;
    const int*   dst   = ei + E;
    const int*   batch = (const int*)d_in[2];
    const float* W1    = (const float*)d_in[3];
    const float* b1    = (const float*)d_in[4];
    const float* W2    = (const float*)d_in[5];
    const float* b2    = (const float*)d_in[6];
    float* out = (float*)d_out;

    int nb = (n + 255) >> 8;            // buckets of 256 nodes

    char* p = (char*)d_ws;
    auto carve = [&](size_t bytes) {
        void* r = (void*)p;
        p += (bytes + 63) & ~(size_t)63;
        return r;
    };
    int*            bcnt   = (int*)carve(NB_MAX * 4);
    int*            packed = (int*)carve((size_t)nb * CAPB * 4);
    int*            sidx2  = (int*)carve((size_t)nb * CAPB * 4);
    int*            noffs  = (int*)carve((size_t)n * 4);
    int*            ndeg   = (int*)carve((size_t)n * 4);
    float*          dinv   = (float*)carve((size_t)n * 4);
    unsigned short* hs     = (unsigned short*)carve((size_t)n * 16 * 2);
    float*          hw     = (float*)carve((size_t)n * 4);

    hipMemsetAsync(d_out, 0, (size_t)out_size * sizeof(float), stream);
    hipMemsetAsync(bcnt, 0, NB_MAX * sizeof(int), stream);

    k_scatter<<<(E + CHUNK - 1) / CHUNK, 512, 0, stream>>>(src, dst, bcnt, packed, E);
    k_dinv<<<nb, 512, 0, stream>>>(packed, bcnt, dinv, noffs, ndeg, n);
    k_gemm1<<<(n + 15) / 16, 256, 0, stream>>>(x, W1, dinv, hs, n);
    k_fused1<<<nb, 512, 0, stream>>>(packed, bcnt, noffs, ndeg, sidx2,
                                     (const uint4*)hs, dinv, b1, W2, hw, n);
    k_agg2<<<nb, 256, 0, stream>>>(hw, noffs, ndeg, sidx2, dinv, b2, batch, out, n);
}

// Round 8
// 148.041 us; speedup vs baseline: 20.6517x; 1.1614x over previous
//
#include <hip/hip_runtime.h>

#define NB_MAX   512      // max buckets (n <= 131072)
#define CHUNK    8192     // edges per scatter block
#define CAPB     16384    // slots per bucket region
#define SORT_CAP 12288    // LDS staging capacity in k_sort2 (49KB)

__device__ inline unsigned short f2bf(float f) {   // round-to-nearest-even bf16
    unsigned u = __float_as_uint(f);
    u += 0x7FFFu + ((u >> 16) & 1u);
    return (unsigned short)(u >> 16);
}

// ---- pass 1: LDS bucket-sort each chunk, reserve space in fixed bucket
//      regions via one atomic per (block,bucket), coalesced run writes ----
__global__ __launch_bounds__(512) void k_scatter(const int* __restrict__ src,
                                                 const int* __restrict__ dst,
                                                 int* __restrict__ bcnt,
                                                 int* __restrict__ packed,
                                                 int E) {
    __shared__ int lh[NB_MAX];
    __shared__ int lscan[NB_MAX];
    __shared__ int ldelta[NB_MAX];
    __shared__ int sorted[CHUNK];
    __shared__ unsigned short sbkt[CHUNK];
    int t = threadIdx.x;
    int e0 = blockIdx.x * CHUNK;
    int e1 = min(e0 + CHUNK, E);
    int cnt = e1 - e0;
    lh[t] = 0;
    __syncthreads();
    for (int e = e0 + t; e < e1; e += 512) atomicAdd(&lh[dst[e] >> 8], 1);
    __syncthreads();
    int v = lh[t];
    lscan[t] = v;
    __syncthreads();
    for (int o = 1; o < 512; o <<= 1) {
        int u = (t >= o) ? lscan[t - o] : 0;
        __syncthreads();
        lscan[t] += u;
        __syncthreads();
    }
    int ex = lscan[t] - v;
    int gbase = v ? atomicAdd(&bcnt[t], v) : 0;
    lh[t] = ex;
    ldelta[t] = t * CAPB + gbase - ex;
    __syncthreads();
    for (int e = e0 + t; e < e1; e += 512) {
        int d = dst[e];
        int b = d >> 8;
        int r = atomicAdd(&lh[b], 1);
        sorted[r] = src[e] | ((d & 255) << 24);
        sbkt[r] = (unsigned short)b;
    }
    __syncthreads();
    for (int i = t; i < cnt; i += 512)
        packed[i + ldelta[sbkt[i]]] = sorted[i];
}

// ---- pass 2: per-bucket dst-sort via LDS staging -> coalesced sidx2 writes,
//      plus dinv/noffs/ndeg ----
__global__ __launch_bounds__(512) void k_sort2(const int* __restrict__ packed,
                                               const int* __restrict__ bcnt,
                                               int* __restrict__ sidx2,
                                               int* __restrict__ noffs,
                                               int* __restrict__ ndeg,
                                               float* __restrict__ dinv, int n) {
    __shared__ int hist[256];
    __shared__ int scan[256];
    __shared__ int curs[256];
    __shared__ int sorted[SORT_CAP];
    int t = threadIdx.x, b = blockIdx.x;
    int seg0 = b * CAPB, cnt = bcnt[b];
    if (t < 256) hist[t] = 0;
    __syncthreads();
    for (int e = t; e < cnt; e += 512)
        atomicAdd(&hist[(unsigned)packed[seg0 + e] >> 24], 1);
    __syncthreads();
    int v = 0;
    if (t < 256) { v = hist[t]; scan[t] = v; }
    __syncthreads();
    for (int o = 1; o < 256; o <<= 1) {
        int u = (t < 256 && t >= o) ? scan[t - o] : 0;
        __syncthreads();
        if (t < 256) scan[t] += u;
        __syncthreads();
    }
    int ex = 0;
    if (t < 256) {
        ex = scan[t] - v;
        int node = (b << 8) + t;
        if (node < n) {
            noffs[node] = seg0 + ex;
            ndeg[node] = v;
            dinv[node] = rsqrtf((float)v + 1.0f);
        }
    }
    if (cnt <= SORT_CAP) {
        if (t < 256) curs[t] = ex;
        __syncthreads();
        for (int e = t; e < cnt; e += 512) {
            int p = packed[seg0 + e];
            int dl = (int)((unsigned)p >> 24);
            int r = atomicAdd(&curs[dl], 1);
            sorted[r] = p & 0xFFFFFF;
        }
        __syncthreads();
        for (int i = t; i < cnt; i += 512)          // coalesced streaming write
            sidx2[seg0 + i] = sorted[i];
    } else {                                        // safety fallback
        if (t < 256) curs[t] = seg0 + ex;
        __syncthreads();
        for (int e = t; e < cnt; e += 512) {
            int p = packed[seg0 + e];
            int dl = (int)((unsigned)p >> 24);
            int r = atomicAdd(&curs[dl], 1);
            sidx2[r] = p & 0xFFFFFF;
        }
    }
}

// ---- hs = bf16((x @ W1) * dinv)  (N x 128 @ 128 x 16) ----
__global__ __launch_bounds__(256) void k_gemm1(const float* __restrict__ x,
                                               const float* __restrict__ W1,
                                               const float* __restrict__ dinv,
                                               unsigned short* __restrict__ hs, int n) {
    __shared__ float sW[128 * 16];
    __shared__ float sX[16 * 128];
    int t = threadIdx.x;
    for (int q = t; q < 2048; q += 256) sW[q] = W1[q];
    int node0 = blockIdx.x * 16;
    const float* xp = x + (size_t)node0 * 128;
    int nrem = n - node0;
    int nload = (nrem >= 16 ? 16 : nrem) * 128;
    for (int q = t; q < nload; q += 256) sX[q] = xp[q];
    __syncthreads();
    int local = t >> 4;
    int col = t & 15;
    int node = node0 + local;
    if (node >= n) return;
    float acc = 0.f;
#pragma unroll 8
    for (int k = 0; k < 128; k++) acc += sX[local * 128 + k] * sW[k * 16 + col];
    hs[(size_t)node * 16 + col] = f2bf(acc * dinv[node]);
}

#define UNPACK_ADD(u)                                        \
    acc[0] += __uint_as_float((u).x << 16);                  \
    acc[1] += __uint_as_float((u).x & 0xFFFF0000u);          \
    acc[2] += __uint_as_float((u).y << 16);                  \
    acc[3] += __uint_as_float((u).y & 0xFFFF0000u);          \
    acc[4] += __uint_as_float((u).z << 16);                  \
    acc[5] += __uint_as_float((u).z & 0xFFFF0000u);          \
    acc[6] += __uint_as_float((u).w << 16);                  \
    acc[7] += __uint_as_float((u).w & 0xFFFF0000u);

// ---- layer-1: CSR register-accumulate, 2 lanes/node, 4 gathers in flight ----
__global__ __launch_bounds__(256) void k_agg1(const uint4* __restrict__ hs4,
                                              const int* __restrict__ noffs,
                                              const int* __restrict__ ndeg,
                                              const int* __restrict__ sidx2,
                                              const float* __restrict__ dinv,
                                              const float* __restrict__ b1,
                                              const float* __restrict__ W2,
                                              float* __restrict__ hw, int n) {
    int tid = blockIdx.x * 256 + threadIdx.x;
    int node = tid >> 1, q = tid & 1;
    if (node >= n) return;
    float acc[8];
    uint4 u0 = hs4[(size_t)node * 2 + q];      // self-loop row (pre-scaled)
    acc[0] = __uint_as_float(u0.x << 16);
    acc[1] = __uint_as_float(u0.x & 0xFFFF0000u);
    acc[2] = __uint_as_float(u0.y << 16);
    acc[3] = __uint_as_float(u0.y & 0xFFFF0000u);
    acc[4] = __uint_as_float(u0.z << 16);
    acc[5] = __uint_as_float(u0.z & 0xFFFF0000u);
    acc[6] = __uint_as_float(u0.w << 16);
    acc[7] = __uint_as_float(u0.w & 0xFFFF0000u);
    int e0 = noffs[node], e1 = e0 + ndeg[node];
    int e = e0;
    for (; e + 3 < e1; e += 4) {               // 4 gathers in flight
        int s0 = sidx2[e], s1 = sidx2[e + 1];
        int s2 = sidx2[e + 2], s3 = sidx2[e + 3];
        uint4 a = hs4[(size_t)s0 * 2 + q];
        uint4 c = hs4[(size_t)s1 * 2 + q];
        uint4 d = hs4[(size_t)s2 * 2 + q];
        uint4 f = hs4[(size_t)s3 * 2 + q];
        UNPACK_ADD(a) UNPACK_ADD(c) UNPACK_ADD(d) UNPACK_ADD(f)
    }
    for (; e < e1; e++) {
        uint4 a = hs4[(size_t)sidx2[e] * 2 + q];
        UNPACK_ADD(a)
    }
    float di = dinv[node];
    int base = q * 8;
    float r = 0.f;
#pragma unroll
    for (int j = 0; j < 8; j++)
        r += fmaxf(di * acc[j] + b1[base + j], 0.f) * W2[base + j];
    r += __shfl_down(r, 1, 2);
    if (q == 0) hw[node] = r * di;              // pre-scaled for layer 2
}

// ---- layer-2: CSR register-accumulate + b2 + segmented pool (batch sorted) ----
__global__ __launch_bounds__(256) void k_agg2(const float* __restrict__ hw,
                                              const int* __restrict__ noffs,
                                              const int* __restrict__ ndeg,
                                              const int* __restrict__ sidx2,
                                              const float* __restrict__ dinv,
                                              const float* __restrict__ b2,
                                              const int* __restrict__ batch,
                                              float* __restrict__ out, int n) {
    __shared__ float v[256];
    __shared__ int g[256];
    int t = threadIdx.x;
    int i = blockIdx.x * 256 + t;
    float val = 0.f;
    int gid = -1;
    if (i < n) {
        float acc = hw[i];                      // self-loop
        int e0 = noffs[i], e1 = e0 + ndeg[i];
        int e = e0;
        for (; e + 1 < e1; e += 2) {
            float a = hw[sidx2[e]];
            float c = hw[sidx2[e + 1]];
            acc += a + c;
        }
        if (e < e1) acc += hw[sidx2[e]];
        val = dinv[i] * acc + b2[0];
        gid = batch[i];
    }
    v[t] = val;
    g[t] = gid;
    __syncthreads();
    if (gid >= 0 && (t == 0 || g[t - 1] != gid)) {
        float s = val;
        for (int q = t + 1; q < 256 && g[q] == gid; q++) s += v[q];
        atomicAdd(&out[gid], s);
    }
}

extern "C" void kernel_launch(void* const* d_in, const int* in_sizes, int n_in,
                              void* d_out, int out_size, void* d_ws, size_t ws_size,
                              hipStream_t stream) {
    int n = in_sizes[0] / 128;
    int E = in_sizes[1] / 2;
    const float* x     = (const float*)d_in[0];
    const int*   ei    = (const int*)d_in[1];
    const int*   src   = ei;
    const int*   dst   = ei + E;
    const int*   batch = (const int*)d_in[2];
    const float* W1    = (const float*)d_in[3];
    const float* b1    = (const float*)d_in[4];
    const float* W2    = (const float*)d_in[5];
    const float* b2    = (const float*)d_in[6];
    float* out = (float*)d_out;

    int nb = (n + 255) >> 8;

    char* p = (char*)d_ws;
    auto carve = [&](size_t bytes) {
        void* r = (void*)p;
        p += (bytes + 63) & ~(size_t)63;
        return r;
    };
    int*            bcnt   = (int*)carve(NB_MAX * 4);
    int*            packed = (int*)carve((size_t)nb * CAPB * 4);
    int*            sidx2  = (int*)carve((size_t)nb * CAPB * 4);
    int*            noffs  = (int*)carve((size_t)n * 4);
    int*            ndeg   = (int*)carve((size_t)n * 4);
    float*          dinv   = (float*)carve((size_t)n * 4);
    unsigned short* hs     = (unsigned short*)carve((size_t)n * 16 * 2);
    float*          hw     = (float*)carve((size_t)n * 4);

    hipMemsetAsync(d_out, 0, (size_t)out_size * sizeof(float), stream);
    hipMemsetAsync(bcnt, 0, NB_MAX * sizeof(int), stream);

    k_scatter<<<(E + CHUNK - 1) / CHUNK, 512, 0, stream>>>(src, dst, bcnt, packed, E);
    k_sort2<<<nb, 512, 0, stream>>>(packed, bcnt, sidx2, noffs, ndeg, dinv, n);
    k_gemm1<<<(n + 15) / 16, 256, 0, stream>>>(x, W1, dinv, hs, n);
    k_agg1<<<((size_t)n * 2 + 255) / 256, 256, 0, stream>>>((const uint4*)hs, noffs, ndeg,
                                                            sidx2, dinv, b1, W2, hw, n);
    k_agg2<<<nb, 256, 0, stream>>>(hw, noffs, ndeg, sidx2, dinv, b2, batch, out, n);
}

// Round 9
// 132.810 us; speedup vs baseline: 23.0200x; 1.1147x over previous
//
#include <hip/hip_runtime.h>

#define NB_MAX   512      // max buckets (n <= 131072)
#define CHUNK    8192     // edges per scatter block
#define CAPB     16384    // slots per bucket region
#define SORT_CAP 12288    // LDS staging capacity in k_sort2 (48KB)

__device__ inline unsigned short f2bf(float f) {   // round-to-nearest-even bf16
    unsigned u = __float_as_uint(f);
    u += 0x7FFFu + ((u >> 16) & 1u);
    return (unsigned short)(u >> 16);
}

// ---- zero d_out (G floats) and bcnt (NB_MAX ints) in one dispatch ----
__global__ void k_zero(float* __restrict__ out, int g, int* __restrict__ bcnt) {
    int t = blockIdx.x * blockDim.x + threadIdx.x;
    if (t < g) out[t] = 0.f;
    if (t < NB_MAX) bcnt[t] = 0;
}

// ---- pass 1: LDS bucket-sort each chunk, reserve space in fixed bucket
//      regions via one atomic per (block,bucket), coalesced run writes ----
__global__ __launch_bounds__(512) void k_scatter(const int* __restrict__ src,
                                                 const int* __restrict__ dst,
                                                 int* __restrict__ bcnt,
                                                 int* __restrict__ packed,
                                                 int E) {
    __shared__ int lh[NB_MAX];
    __shared__ int lscan[NB_MAX];
    __shared__ int ldelta[NB_MAX];
    __shared__ int sorted[CHUNK];
    __shared__ unsigned short sbkt[CHUNK];
    int t = threadIdx.x;
    int e0 = blockIdx.x * CHUNK;
    int e1 = min(e0 + CHUNK, E);
    int cnt = e1 - e0;
    lh[t] = 0;
    __syncthreads();
    for (int e = e0 + t; e < e1; e += 512) atomicAdd(&lh[dst[e] >> 8], 1);
    __syncthreads();
    int v = lh[t];
    lscan[t] = v;
    __syncthreads();
    for (int o = 1; o < 512; o <<= 1) {
        int u = (t >= o) ? lscan[t - o] : 0;
        __syncthreads();
        lscan[t] += u;
        __syncthreads();
    }
    int ex = lscan[t] - v;
    int gbase = v ? atomicAdd(&bcnt[t], v) : 0;
    lh[t] = ex;
    ldelta[t] = t * CAPB + gbase - ex;
    __syncthreads();
    for (int e = e0 + t; e < e1; e += 512) {
        int d = dst[e];
        int b = d >> 8;
        int r = atomicAdd(&lh[b], 1);
        sorted[r] = src[e] | ((d & 255) << 24);
        sbkt[r] = (unsigned short)b;
    }
    __syncthreads();
    for (int i = t; i < cnt; i += 512)
        packed[i + ldelta[sbkt[i]]] = sorted[i];
}

// ---- pass 2: per-bucket dst-sort via LDS staging -> coalesced sidx2 writes,
//      plus dinv/noffs/ndeg ----
__global__ __launch_bounds__(512) void k_sort2(const int* __restrict__ packed,
                                               const int* __restrict__ bcnt,
                                               int* __restrict__ sidx2,
                                               int* __restrict__ noffs,
                                               int* __restrict__ ndeg,
                                               float* __restrict__ dinv, int n) {
    __shared__ int hist[256];
    __shared__ int scan[256];
    __shared__ int curs[256];
    __shared__ int sorted[SORT_CAP];
    int t = threadIdx.x, b = blockIdx.x;
    int seg0 = b * CAPB, cnt = bcnt[b];
    if (t < 256) hist[t] = 0;
    __syncthreads();
    for (int e = t; e < cnt; e += 512)
        atomicAdd(&hist[(unsigned)packed[seg0 + e] >> 24], 1);
    __syncthreads();
    int v = 0;
    if (t < 256) { v = hist[t]; scan[t] = v; }
    __syncthreads();
    for (int o = 1; o < 256; o <<= 1) {
        int u = (t < 256 && t >= o) ? scan[t - o] : 0;
        __syncthreads();
        if (t < 256) scan[t] += u;
        __syncthreads();
    }
    int ex = 0;
    if (t < 256) {
        ex = scan[t] - v;
        int node = (b << 8) + t;
        if (node < n) {
            noffs[node] = seg0 + ex;
            ndeg[node] = v;
            dinv[node] = rsqrtf((float)v + 1.0f);
        }
    }
    if (cnt <= SORT_CAP) {
        if (t < 256) curs[t] = ex;
        __syncthreads();
        for (int e = t; e < cnt; e += 512) {
            int p = packed[seg0 + e];
            int dl = (int)((unsigned)p >> 24);
            int r = atomicAdd(&curs[dl], 1);
            sorted[r] = p & 0xFFFFFF;
        }
        __syncthreads();
        for (int i = t; i < cnt; i += 512)          // coalesced streaming write
            sidx2[seg0 + i] = sorted[i];
    } else {                                        // safety fallback
        if (t < 256) curs[t] = seg0 + ex;
        __syncthreads();
        for (int e = t; e < cnt; e += 512) {
            int p = packed[seg0 + e];
            int dl = (int)((unsigned)p >> 24);
            int r = atomicAdd(&curs[dl], 1);
            sidx2[r] = p & 0xFFFFFF;
        }
    }
}

// ---- hs = bf16((x @ W1) * dinv): 256 nodes/block, 4x4 register tile/thread ----
__global__ __launch_bounds__(256) void k_gemm1(const float* __restrict__ x,
                                               const float* __restrict__ W1,
                                               const float* __restrict__ dinv,
                                               unsigned short* __restrict__ hs, int n) {
    __shared__ float sW[128 * 16];
    __shared__ float sXT[32 * 260];     // k-major transposed chunk, pad 260
    int t = threadIdx.x;
    for (int q = t; q < 2048; q += 256) sW[q] = W1[q];
    int node0 = blockIdx.x * 256;
    int ng = t >> 2, cg = t & 3;        // 64 node-groups x 4 col-groups
    int sub = t & 7, rbase = t >> 3;    // loader: 8 threads/row, 32 rows/pass
    float acc[4][4];
#pragma unroll
    for (int i = 0; i < 4; i++)
#pragma unroll
        for (int j = 0; j < 4; j++) acc[i][j] = 0.f;
    for (int kc = 0; kc < 4; kc++) {    // 4 k-chunks of 32
        __syncthreads();                // also covers sW load on first iter
#pragma unroll
        for (int pass = 0; pass < 8; pass++) {
            int row = pass * 32 + rbase;
            int node = node0 + row;
            const float* xp = x + (size_t)min(node, n - 1) * 128 + kc * 32 + sub * 4;
            float4 v = *(const float4*)xp;
            int k0 = sub * 4;
            sXT[(k0 + 0) * 260 + row] = v.x;
            sXT[(k0 + 1) * 260 + row] = v.y;
            sXT[(k0 + 2) * 260 + row] = v.z;
            sXT[(k0 + 3) * 260 + row] = v.w;
        }
        __syncthreads();
        const float* wbase = sW + kc * 32 * 16 + cg * 4;
#pragma unroll 8
        for (int k = 0; k < 32; k++) {
            float4 xv = *(const float4*)&sXT[k * 260 + ng * 4];
            float4 wv = *(const float4*)&wbase[k * 16];
            acc[0][0] += xv.x * wv.x; acc[0][1] += xv.x * wv.y;
            acc[0][2] += xv.x * wv.z; acc[0][3] += xv.x * wv.w;
            acc[1][0] += xv.y * wv.x; acc[1][1] += xv.y * wv.y;
            acc[1][2] += xv.y * wv.z; acc[1][3] += xv.y * wv.w;
            acc[2][0] += xv.z * wv.x; acc[2][1] += xv.z * wv.y;
            acc[2][2] += xv.z * wv.z; acc[2][3] += xv.z * wv.w;
            acc[3][0] += xv.w * wv.x; acc[3][1] += xv.w * wv.y;
            acc[3][2] += xv.w * wv.z; acc[3][3] += xv.w * wv.w;
        }
    }
#pragma unroll
    for (int i = 0; i < 4; i++) {
        int node = node0 + ng * 4 + i;
        if (node < n) {
            float di = dinv[node];
            ushort4 o;
            o.x = f2bf(acc[i][0] * di);
            o.y = f2bf(acc[i][1] * di);
            o.z = f2bf(acc[i][2] * di);
            o.w = f2bf(acc[i][3] * di);
            *(ushort4*)&hs[(size_t)node * 16 + cg * 4] = o;
        }
    }
}

#define UNPACK_ADD(u)                                        \
    acc[0] += __uint_as_float((u).x << 16);                  \
    acc[1] += __uint_as_float((u).x & 0xFFFF0000u);          \
    acc[2] += __uint_as_float((u).y << 16);                  \
    acc[3] += __uint_as_float((u).y & 0xFFFF0000u);          \
    acc[4] += __uint_as_float((u).z << 16);                  \
    acc[5] += __uint_as_float((u).z & 0xFFFF0000u);          \
    acc[6] += __uint_as_float((u).w << 16);                  \
    acc[7] += __uint_as_float((u).w & 0xFFFF0000u);

// ---- layer-1: CSR register-accumulate, 2 lanes/node, 4 gathers in flight ----
__global__ __launch_bounds__(256) void k_agg1(const uint4* __restrict__ hs4,
                                              const int* __restrict__ noffs,
                                              const int* __restrict__ ndeg,
                                              const int* __restrict__ sidx2,
                                              const float* __restrict__ dinv,
                                              const float* __restrict__ b1,
                                              const float* __restrict__ W2,
                                              float* __restrict__ hw, int n) {
    int tid = blockIdx.x * 256 + threadIdx.x;
    int node = tid >> 1, q = tid & 1;
    if (node >= n) return;
    float acc[8];
    uint4 u0 = hs4[(size_t)node * 2 + q];      // self-loop row (pre-scaled)
    acc[0] = __uint_as_float(u0.x << 16);
    acc[1] = __uint_as_float(u0.x & 0xFFFF0000u);
    acc[2] = __uint_as_float(u0.y << 16);
    acc[3] = __uint_as_float(u0.y & 0xFFFF0000u);
    acc[4] = __uint_as_float(u0.z << 16);
    acc[5] = __uint_as_float(u0.z & 0xFFFF0000u);
    acc[6] = __uint_as_float(u0.w << 16);
    acc[7] = __uint_as_float(u0.w & 0xFFFF0000u);
    int e0 = noffs[node], e1 = e0 + ndeg[node];
    int e = e0;
    for (; e + 3 < e1; e += 4) {               // 4 gathers in flight
        int s0 = sidx2[e], s1 = sidx2[e + 1];
        int s2 = sidx2[e + 2], s3 = sidx2[e + 3];
        uint4 a = hs4[(size_t)s0 * 2 + q];
        uint4 c = hs4[(size_t)s1 * 2 + q];
        uint4 d = hs4[(size_t)s2 * 2 + q];
        uint4 f = hs4[(size_t)s3 * 2 + q];
        UNPACK_ADD(a) UNPACK_ADD(c) UNPACK_ADD(d) UNPACK_ADD(f)
    }
    for (; e < e1; e++) {
        uint4 a = hs4[(size_t)sidx2[e] * 2 + q];
        UNPACK_ADD(a)
    }
    float di = dinv[node];
    int base = q * 8;
    float r = 0.f;
#pragma unroll
    for (int j = 0; j < 8; j++)
        r += fmaxf(di * acc[j] + b1[base + j], 0.f) * W2[base + j];
    r += __shfl_down(r, 1, 2);
    if (q == 0) hw[node] = r * di;              // pre-scaled for layer 2
}

// ---- layer-2: CSR register-accumulate + b2 + segmented pool (batch sorted) ----
__global__ __launch_bounds__(256) void k_agg2(const float* __restrict__ hw,
                                              const int* __restrict__ noffs,
                                              const int* __restrict__ ndeg,
                                              const int* __restrict__ sidx2,
                                              const float* __restrict__ dinv,
                                              const float* __restrict__ b2,
                                              const int* __restrict__ batch,
                                              float* __restrict__ out, int n) {
    __shared__ float v[256];
    __shared__ int g[256];
    int t = threadIdx.x;
    int i = blockIdx.x * 256 + t;
    float val = 0.f;
    int gid = -1;
    if (i < n) {
        float acc = hw[i];                      // self-loop
        int e0 = noffs[i], e1 = e0 + ndeg[i];
        int e = e0;
        for (; e + 1 < e1; e += 2) {
            float a = hw[sidx2[e]];
            float c = hw[sidx2[e + 1]];
            acc += a + c;
        }
        if (e < e1) acc += hw[sidx2[e]];
        val = dinv[i] * acc + b2[0];
        gid = batch[i];
    }
    v[t] = val;
    g[t] = gid;
    __syncthreads();
    if (gid >= 0 && (t == 0 || g[t - 1] != gid)) {
        float s = val;
        for (int q = t + 1; q < 256 && g[q] == gid; q++) s += v[q];
        atomicAdd(&out[gid], s);
    }
}

extern "C" void kernel_launch(void* const* d_in, const int* in_sizes, int n_in,
                              void* d_out, int out_size, void* d_ws, size_t ws_size,
                              hipStream_t stream) {
    int n = in_sizes[0] / 128;
    int E = in_sizes[1] / 2;
    const float* x     = (const float*)d_in[0];
    const int*   ei    = (const int*)d_in[1];
    const int*   src   = ei;
    const int*   dst   = ei + E;
    const int*   batch = (const int*)d_in[2];
    const float* W1    = (const float*)d_in[3];
    const float* b1    = (const float*)d_in[4];
    const float* W2    = (const float*)d_in[5];
    const float* b2    = (const float*)d_in[6];
    float* out = (float*)d_out;

    int nb = (n + 255) >> 8;

    char* p = (char*)d_ws;
    auto carve = [&](size_t bytes) {
        void* r = (void*)p;
        p += (bytes + 63) & ~(size_t)63;
        return r;
    };
    int*            bcnt   = (int*)carve(NB_MAX * 4);
    int*            packed = (int*)carve((size_t)nb * CAPB * 4);
    int*            sidx2  = (int*)carve((size_t)nb * CAPB * 4);
    int*            noffs  = (int*)carve((size_t)n * 4);
    int*            ndeg   = (int*)carve((size_t)n * 4);
    float*          dinv   = (float*)carve((size_t)n * 4);
    unsigned short* hs     = (unsigned short*)carve((size_t)n * 16 * 2);
    float*          hw     = (float*)carve((size_t)n * 4);

    k_zero<<<(out_size + 1023) / 1024, 1024, 0, stream>>>(out, out_size, bcnt);
    k_scatter<<<(E + CHUNK - 1) / CHUNK, 512, 0, stream>>>(src, dst, bcnt, packed, E);
    k_sort2<<<nb, 512, 0, stream>>>(packed, bcnt, sidx2, noffs, ndeg, dinv, n);
    k_gemm1<<<nb, 256, 0, stream>>>(x, W1, dinv, hs, n);
    k_agg1<<<((size_t)n * 2 + 255) / 256, 256, 0, stream>>>((const uint4*)hs, noffs, ndeg,
                                                            sidx2, dinv, b1, W2, hw, n);
    k_agg2<<<nb, 256, 0, stream>>>(hw, noffs, ndeg, sidx2, dinv, b2, batch, out, n);
}

// Round 10
// 120.926 us; speedup vs baseline: 25.2824x; 1.0983x over previous
//
#include <hip/hip_runtime.h>

#define NB_MAX   512      // max buckets (n <= 131072)
#define CHUNK    8192     // edges per scatter block
#define CAPB     16384    // slots per bucket region
#define SORT_CAP 12288    // LDS staging capacity in k_sortgemm (48KB)

__device__ inline unsigned short f2bf(float f) {   // round-to-nearest-even bf16
    unsigned u = __float_as_uint(f);
    u += 0x7FFFu + ((u >> 16) & 1u);
    return (unsigned short)(u >> 16);
}

// ---- zero d_out (G floats) and bcnt (NB_MAX ints) in one dispatch ----
__global__ void k_zero(float* __restrict__ out, int g, int* __restrict__ bcnt) {
    int t = blockIdx.x * blockDim.x + threadIdx.x;
    if (t < g) out[t] = 0.f;
    if (t < NB_MAX) bcnt[t] = 0;
}

// ---- pass 1: LDS bucket-sort each chunk, reserve space in fixed bucket
//      regions via one atomic per (block,bucket), coalesced run writes ----
__global__ __launch_bounds__(512) void k_scatter(const int* __restrict__ src,
                                                 const int* __restrict__ dst,
                                                 int* __restrict__ bcnt,
                                                 int* __restrict__ packed,
                                                 int E) {
    __shared__ int lh[NB_MAX];
    __shared__ int lscan[NB_MAX];
    __shared__ int ldelta[NB_MAX];
    __shared__ int sorted[CHUNK];
    __shared__ unsigned short sbkt[CHUNK];
    int t = threadIdx.x;
    int e0 = blockIdx.x * CHUNK;
    int e1 = min(e0 + CHUNK, E);
    int cnt = e1 - e0;
    lh[t] = 0;
    __syncthreads();
    for (int e = e0 + t; e < e1; e += 512) atomicAdd(&lh[dst[e] >> 8], 1);
    __syncthreads();
    int v = lh[t];
    lscan[t] = v;
    __syncthreads();
    for (int o = 1; o < 512; o <<= 1) {
        int u = (t >= o) ? lscan[t - o] : 0;
        __syncthreads();
        lscan[t] += u;
        __syncthreads();
    }
    int ex = lscan[t] - v;
    int gbase = v ? atomicAdd(&bcnt[t], v) : 0;
    lh[t] = ex;
    ldelta[t] = t * CAPB + gbase - ex;
    __syncthreads();
    for (int e = e0 + t; e < e1; e += 512) {
        int d = dst[e];
        int b = d >> 8;
        int r = atomicAdd(&lh[b], 1);
        sorted[r] = src[e] | ((d & 255) << 24);
        sbkt[r] = (unsigned short)b;
    }
    __syncthreads();
    for (int i = t; i < cnt; i += 512)
        packed[i + ldelta[sbkt[i]]] = sorted[i];
}

// ---- fused pass 2 + feature GEMM ----
// phase A: per-bucket dst-sort via LDS staging -> coalesced sidx2 writes,
//          dinv/noffs/ndeg (dinv also kept in LDS)
// phase B: hs = bf16((x @ W1) * dinv) for this block's 256 nodes
//          (sorted buffer reused as the transposed x tile)
__global__ __launch_bounds__(512) void k_sortgemm(const int* __restrict__ packed,
                                                  const int* __restrict__ bcnt,
                                                  const float* __restrict__ x,
                                                  const float* __restrict__ W1,
                                                  int* __restrict__ sidx2,
                                                  int* __restrict__ noffs,
                                                  int* __restrict__ ndeg,
                                                  float* __restrict__ dinv,
                                                  unsigned short* __restrict__ hs,
                                                  int n) {
    __shared__ int hist[256];
    __shared__ int scan[256];
    __shared__ int curs[256];
    __shared__ float sdinv[256];
    __shared__ float sW[128 * 16];                  // 8KB
    __shared__ __align__(16) char smem[SORT_CAP * 4];  // 48KB: sorted ints, then sXT
    int* sorted = (int*)smem;
    float* sXT = (float*)smem;                      // 32 x 260 floats (33.3KB)

    int t = threadIdx.x, b = blockIdx.x;
    int seg0 = b * CAPB, cnt = bcnt[b];
    int node0 = b << 8;

    for (int q = t; q < 2048; q += 512) sW[q] = W1[q];   // overlaps phase A
    if (t < 256) hist[t] = 0;
    __syncthreads();
    for (int e = t; e < cnt; e += 512)
        atomicAdd(&hist[(unsigned)packed[seg0 + e] >> 24], 1);
    __syncthreads();
    int v = 0;
    if (t < 256) { v = hist[t]; scan[t] = v; }
    __syncthreads();
    for (int o = 1; o < 256; o <<= 1) {
        int u = (t < 256 && t >= o) ? scan[t - o] : 0;
        __syncthreads();
        if (t < 256) scan[t] += u;
        __syncthreads();
    }
    int ex = 0;
    if (t < 256) {
        ex = scan[t] - v;
        float di = rsqrtf((float)v + 1.0f);
        sdinv[t] = di;
        int node = node0 + t;
        if (node < n) {
            noffs[node] = seg0 + ex;
            ndeg[node] = v;
            dinv[node] = di;
        }
    }
    if (cnt <= SORT_CAP) {
        if (t < 256) curs[t] = ex;
        __syncthreads();
        for (int e = t; e < cnt; e += 512) {
            int p = packed[seg0 + e];
            int dl = (int)((unsigned)p >> 24);
            int r = atomicAdd(&curs[dl], 1);
            sorted[r] = p & 0xFFFFFF;
        }
        __syncthreads();
        for (int i = t; i < cnt; i += 512)          // coalesced streaming write
            sidx2[seg0 + i] = sorted[i];
    } else {                                        // safety fallback
        if (t < 256) curs[t] = seg0 + ex;
        __syncthreads();
        for (int e = t; e < cnt; e += 512) {
            int p = packed[seg0 + e];
            int dl = (int)((unsigned)p >> 24);
            int r = atomicAdd(&curs[dl], 1);
            sidx2[r] = p & 0xFFFFFF;
        }
    }

    // ---- phase B: GEMM, 4x4 register tile on threads 0..255 ----
    int ng = t >> 2, cg = t & 3;
    float acc[4][4];
#pragma unroll
    for (int i = 0; i < 4; i++)
#pragma unroll
        for (int j = 0; j < 4; j++) acc[i][j] = 0.f;
    for (int kc = 0; kc < 4; kc++) {
        __syncthreads();                            // sorted dead / prev sXT consumed
#pragma unroll
        for (int pass = 0; pass < 4; pass++) {      // 512 loaders: 64 rows/pass
            int row = pass * 64 + (t >> 3);
            int node = node0 + row;
            const float* xp = x + (size_t)min(node, n - 1) * 128 + kc * 32 + (t & 7) * 4;
            float4 vv = *(const float4*)xp;
            int k0 = (t & 7) * 4;
            sXT[(k0 + 0) * 260 + row] = vv.x;
            sXT[(k0 + 1) * 260 + row] = vv.y;
            sXT[(k0 + 2) * 260 + row] = vv.z;
            sXT[(k0 + 3) * 260 + row] = vv.w;
        }
        __syncthreads();
        if (t < 256) {
            const float* wbase = sW + kc * 32 * 16 + cg * 4;
#pragma unroll 8
            for (int k = 0; k < 32; k++) {
                float4 xv = *(const float4*)&sXT[k * 260 + ng * 4];
                float4 wv = *(const float4*)&wbase[k * 16];
                acc[0][0] += xv.x * wv.x; acc[0][1] += xv.x * wv.y;
                acc[0][2] += xv.x * wv.z; acc[0][3] += xv.x * wv.w;
                acc[1][0] += xv.y * wv.x; acc[1][1] += xv.y * wv.y;
                acc[1][2] += xv.y * wv.z; acc[1][3] += xv.y * wv.w;
                acc[2][0] += xv.z * wv.x; acc[2][1] += xv.z * wv.y;
                acc[2][2] += xv.z * wv.z; acc[2][3] += xv.z * wv.w;
                acc[3][0] += xv.w * wv.x; acc[3][1] += xv.w * wv.y;
                acc[3][2] += xv.w * wv.z; acc[3][3] += xv.w * wv.w;
            }
        }
    }
    if (t < 256) {
#pragma unroll
        for (int i = 0; i < 4; i++) {
            int local = ng * 4 + i;
            int node = node0 + local;
            if (node < n) {
                float di = sdinv[local];
                ushort4 o;
                o.x = f2bf(acc[i][0] * di);
                o.y = f2bf(acc[i][1] * di);
                o.z = f2bf(acc[i][2] * di);
                o.w = f2bf(acc[i][3] * di);
                *(ushort4*)&hs[(size_t)node * 16 + cg * 4] = o;
            }
        }
    }
}

#define UNPACK_ADD(u)                                        \
    acc[0] += __uint_as_float((u).x << 16);                  \
    acc[1] += __uint_as_float((u).x & 0xFFFF0000u);          \
    acc[2] += __uint_as_float((u).y << 16);                  \
    acc[3] += __uint_as_float((u).y & 0xFFFF0000u);          \
    acc[4] += __uint_as_float((u).z << 16);                  \
    acc[5] += __uint_as_float((u).z & 0xFFFF0000u);          \
    acc[6] += __uint_as_float((u).w << 16);                  \
    acc[7] += __uint_as_float((u).w & 0xFFFF0000u);

// ---- layer-1: CSR register-accumulate, 2 lanes/node, 8 gathers in flight ----
__global__ __launch_bounds__(256) void k_agg1(const uint4* __restrict__ hs4,
                                              const int* __restrict__ noffs,
                                              const int* __restrict__ ndeg,
                                              const int* __restrict__ sidx2,
                                              const float* __restrict__ dinv,
                                              const float* __restrict__ b1,
                                              const float* __restrict__ W2,
                                              float* __restrict__ hw, int n) {
    int tid = blockIdx.x * 256 + threadIdx.x;
    int node = tid >> 1, q = tid & 1;
    if (node >= n) return;
    float acc[8];
    uint4 u0 = hs4[(size_t)node * 2 + q];      // self-loop row (pre-scaled)
    acc[0] = __uint_as_float(u0.x << 16);
    acc[1] = __uint_as_float(u0.x & 0xFFFF0000u);
    acc[2] = __uint_as_float(u0.y << 16);
    acc[3] = __uint_as_float(u0.y & 0xFFFF0000u);
    acc[4] = __uint_as_float(u0.z << 16);
    acc[5] = __uint_as_float(u0.z & 0xFFFF0000u);
    acc[6] = __uint_as_float(u0.w << 16);
    acc[7] = __uint_as_float(u0.w & 0xFFFF0000u);
    int e0 = noffs[node], e1 = e0 + ndeg[node];
    int e = e0;
    for (; e + 7 < e1; e += 8) {               // 8 gathers in flight
        int s0 = sidx2[e],     s1 = sidx2[e + 1];
        int s2 = sidx2[e + 2], s3 = sidx2[e + 3];
        int s4 = sidx2[e + 4], s5 = sidx2[e + 5];
        int s6 = sidx2[e + 6], s7 = sidx2[e + 7];
        uint4 a0 = hs4[(size_t)s0 * 2 + q];
        uint4 a1 = hs4[(size_t)s1 * 2 + q];
        uint4 a2 = hs4[(size_t)s2 * 2 + q];
        uint4 a3 = hs4[(size_t)s3 * 2 + q];
        uint4 a4 = hs4[(size_t)s4 * 2 + q];
        uint4 a5 = hs4[(size_t)s5 * 2 + q];
        uint4 a6 = hs4[(size_t)s6 * 2 + q];
        uint4 a7 = hs4[(size_t)s7 * 2 + q];
        UNPACK_ADD(a0) UNPACK_ADD(a1) UNPACK_ADD(a2) UNPACK_ADD(a3)
        UNPACK_ADD(a4) UNPACK_ADD(a5) UNPACK_ADD(a6) UNPACK_ADD(a7)
    }
    for (; e < e1; e++) {
        uint4 a = hs4[(size_t)sidx2[e] * 2 + q];
        UNPACK_ADD(a)
    }
    float di = dinv[node];
    int base = q * 8;
    float r = 0.f;
#pragma unroll
    for (int j = 0; j < 8; j++)
        r += fmaxf(di * acc[j] + b1[base + j], 0.f) * W2[base + j];
    r += __shfl_down(r, 1, 2);
    if (q == 0) hw[node] = r * di;              // pre-scaled for layer 2
}

// ---- layer-2: 2 lanes/node CSR accumulate + b2 + segmented pool ----
__global__ __launch_bounds__(256) void k_agg2(const float* __restrict__ hw,
                                              const int* __restrict__ noffs,
                                              const int* __restrict__ ndeg,
                                              const int* __restrict__ sidx2,
                                              const float* __restrict__ dinv,
                                              const float* __restrict__ b2,
                                              const int* __restrict__ batch,
                                              float* __restrict__ out, int n) {
    __shared__ float v[128];
    __shared__ int g[128];
    int t = threadIdx.x;
    int tid = blockIdx.x * 256 + t;
    int i = tid >> 1, q = tid & 1;
    int li = t >> 1;
    float acc = 0.f;
    int gid = -1;
    if (i < n) {
        if (q == 0) acc = hw[i];                // self-loop
        int e0 = noffs[i], e1 = e0 + ndeg[i];
        int e = e0 + q;
        for (; e + 6 < e1; e += 8)              // 4 gathers in flight per lane
            acc += hw[sidx2[e]] + hw[sidx2[e + 2]] + hw[sidx2[e + 4]] + hw[sidx2[e + 6]];
        for (; e < e1; e += 2) acc += hw[sidx2[e]];
    }
    acc += __shfl_down(acc, 1, 2);
    if (i < n && q == 0) {
        v[li] = dinv[i] * acc + b2[0];
        g[li] = batch[i];
    } else if (q == 0) {
        v[li] = 0.f;
        g[li] = -1;
    }
    __syncthreads();
    if (q == 0) {
        int gid2 = g[li];
        if (gid2 >= 0 && (li == 0 || g[li - 1] != gid2)) {   // segment head
            float s = v[li];
            for (int w = li + 1; w < 128 && g[w] == gid2; w++) s += v[w];
            atomicAdd(&out[gid2], s);
        }
    }
}

extern "C" void kernel_launch(void* const* d_in, const int* in_sizes, int n_in,
                              void* d_out, int out_size, void* d_ws, size_t ws_size,
                              hipStream_t stream) {
    int n = in_sizes[0] / 128;
    int E = in_sizes[1] / 2;
    const float* x     = (const float*)d_in[0];
    const int*   ei    = (const int*)d_in[1];
    const int*   src   = ei;
    const int*   dst   = ei + E;
    const int*   batch = (const int*)d_in[2];
    const float* W1    = (const float*)d_in[3];
    const float* b1    = (const float*)d_in[4];
    const float* W2    = (const float*)d_in[5];
    const float* b2    = (const float*)d_in[6];
    float* out = (float*)d_out;

    int nb = (n + 255) >> 8;

    char* p = (char*)d_ws;
    auto carve = [&](size_t bytes) {
        void* r = (void*)p;
        p += (bytes + 63) & ~(size_t)63;
        return r;
    };
    int*            bcnt   = (int*)carve(NB_MAX * 4);
    int*            packed = (int*)carve((size_t)nb * CAPB * 4);
    int*            sidx2  = (int*)carve((size_t)nb * CAPB * 4);
    int*            noffs  = (int*)carve((size_t)n * 4);
    int*            ndeg   = (int*)carve((size_t)n * 4);
    float*          dinv   = (float*)carve((size_t)n * 4);
    unsigned short* hs     = (unsigned short*)carve((size_t)n * 16 * 2);
    float*          hw     = (float*)carve((size_t)n * 4);

    k_zero<<<(out_size + 1023) / 1024, 1024, 0, stream>>>(out, out_size, bcnt);
    k_scatter<<<(E + CHUNK - 1) / CHUNK, 512, 0, stream>>>(src, dst, bcnt, packed, E);
    k_sortgemm<<<nb, 512, 0, stream>>>(packed, bcnt, x, W1, sidx2, noffs, ndeg,
                                       dinv, hs, n);
    k_agg1<<<((size_t)n * 2 + 255) / 256, 256, 0, stream>>>((const uint4*)hs, noffs, ndeg,
                                                            sidx2, dinv, b1, W2, hw, n);
    k_agg2<<<((size_t)n * 2 + 255) / 256, 256, 0, stream>>>(hw, noffs, ndeg, sidx2,
                                                            dinv, b2, batch, out, n);
}